// Round 4
// baseline (6944.362 us; speedup 1.0000x reference)
//
#include <hip/hip_runtime.h>
#include <stdint.h>

// ---------------------------------------------------------------------------
// LSTMSupertaggingModel: segment-mean-pool -> BiLSTM(H=384) -> Linear(C=425)
// B=64, S=512, D=768, W=256, H=384, C=425
//
// V10 = V8 backbone (proven: tagged [b][h] u32 agent mailbox, full-sector
// stores, speculative tagged spin) + XCD-local FAST exchange, made sound:
//  - V9 post-mortem (hang): FAST sc0 stores left DIRTY mailbox lines in an
//    XCD L2; next launch's eviction of those lines clobbered IC copies of
//    the SAME addresses used by the agent path -> consumer spun forever.
//  - Fix 1: FAST uses a DISJOINT per-XCD region htagF[8] (48KB each,
//    claimed by agent-CAS, one clique per XCD). Region x is only ever
//    accessed through L2-x (sc0) in ANY launch -> single coherence point;
//    claimer scrubs the whole region (write-allocate masks stale IC),
//    vmcnt-drains, clique ready-barrier, then steps.
//  - Fix 2: FAST producers DUAL-publish (sc0 -> htagF AND agent -> htag).
//    Agent copy = unconditional liveness.
//  - Fix 3: consumer waves spin FAST <=4096 rounds, then latch to the V8
//    agent path permanently. No placement/coherence theory can hang us.
//  - Kept from V9: LDS XOR swizzle on dedup tile; xp prefetched one step
//    ahead in raw ushort regs, folded AFTER the MFMA.
//  - R5 lesson: Whh/dir = 1.18MB > CU register file -> cross-CU exchange
//    is structural; the game is exchange LATENCY.
// ---------------------------------------------------------------------------

typedef __attribute__((ext_vector_type(8))) short short8;
typedef __attribute__((ext_vector_type(4))) float f32x4;
typedef __attribute__((ext_vector_type(4))) unsigned int u32x4;

static constexpr int Bn = 64, Sn = 512, Dn = 768, Wn = 256, Hn = 384, Cn = 425;
static constexpr int G4H = 4 * Hn;          // 1536
static constexpr int NBT = 4;               // batch tiles of 16
static constexpr int NCK = 6;               // h-chunks of 64 rows per dir
static constexpr int REGW = 2 * 16 * 384;   // words per FAST region (12288 = 48KB)

__device__ __forceinline__ unsigned short f2bf(float f) {
  unsigned int u = __float_as_uint(f);
  u += 0x7FFFu + ((u >> 16) & 1u);          // round-to-nearest-even
  return (unsigned short)(u >> 16);
}
__device__ __forceinline__ float bf2f(unsigned short h) {
  return __uint_as_float(((unsigned int)h) << 16);
}
__device__ __forceinline__ float sigm(float x)  { return 1.f / (1.f + __expf(-x)); }
__device__ __forceinline__ float tanhft(float x){ return 1.f - 2.f / (__expf(2.f * x) + 1.f); }

// async global->LDS, 16B per lane; LDS dest = wave-uniform base + lane*16
#define GLL16(gp, lp) __builtin_amdgcn_global_load_lds( \
  (const __attribute__((address_space(1))) unsigned int*)(gp), \
  (__attribute__((address_space(3))) unsigned int*)(lp), 16, 0, 0)

// ---------------------------------------------------------------------------
// zero comm region through the UC/atomic path (visible to agent-scope loads)
__global__ void zero_comm(unsigned int* p, int nwords) {
  int i = blockIdx.x * 256 + threadIdx.x;
  if (i < nwords)
    __hip_atomic_store(&p[i], 0u, __ATOMIC_RELAXED, __HIP_MEMORY_SCOPE_AGENT);
}

// ---------------------------------------------------------------------------
__global__ void scan_starts(const int* __restrict__ counts, int* __restrict__ starts) {
  int b = blockIdx.x, j = threadIdx.x;      // 64 blocks x 256 threads
  __shared__ int sm[256];
  int c = counts[b * Wn + j];
  sm[j] = c;
  __syncthreads();
  for (int off = 1; off < 256; off <<= 1) {
    int v = (j >= off) ? sm[j - off] : 0;
    __syncthreads();
    sm[j] += v;
    __syncthreads();
  }
  starts[b * Wn + j] = sm[j] - c;           // exclusive
}

// ---------------------------------------------------------------------------
__global__ void prep_cast(const float* __restrict__ Wih_f, const float* __restrict__ Wih_b,
                          const float* __restrict__ Whh_f, const float* __restrict__ Whh_b,
                          const float* __restrict__ Wlin,
                          const float* __restrict__ bih_f, const float* __restrict__ bhh_f,
                          const float* __restrict__ bih_b, const float* __restrict__ bhh_b,
                          unsigned short* __restrict__ wih, unsigned short* __restrict__ whh,
                          unsigned short* __restrict__ wlin, float* __restrict__ biasc) {
  int i = blockIdx.x * 256 + threadIdx.x;
  const int T0 = 3072 * 768;                // Wih both dirs
  const int T1 = 2 * 1536 * 384;            // Whh both dirs
  const int T2 = Cn * 768;                  // Wlin
  const int T3 = 3072;                      // bias
  if (i < T0) {
    int n = i / 768, k = i - n * 768;
    float v = (n < 1536) ? Wih_f[n * 768 + k] : Wih_b[(n - 1536) * 768 + k];
    wih[i] = f2bf(v);
  } else if (i < T0 + T1) {
    int j = i - T0;
    float v = (j < 1536 * 384) ? Whh_f[j] : Whh_b[j - 1536 * 384];
    whh[j] = f2bf(v);
  } else if (i < T0 + T1 + T2) {
    int j = i - T0 - T1;
    wlin[j] = f2bf(Wlin[j]);
  } else if (i < T0 + T1 + T2 + T3) {
    int n = i - T0 - T1 - T2;
    biasc[n] = (n < 1536) ? (bih_f[n] + bhh_f[n]) : (bih_b[n - 1536] + bhh_b[n - 1536]);
  }
}

// ---------------------------------------------------------------------------
// ragged segment mean: f0p[b*S+s][:] = s<W ? mean(f0[b, st..st+cnt)) : f0[b,s]
__global__ void pool_kernel(const float* __restrict__ f0, const int* __restrict__ counts,
                            const int* __restrict__ starts, unsigned short* __restrict__ f0p) {
  int idx = blockIdx.x * 256 + threadIdx.x;           // B*S*192 exact
  int dc = idx % 192;
  int rest = idx / 192;
  int s = rest & 511, b = rest >> 9;
  const float4* f4 = (const float4*)f0;
  float4 v;
  if (s < Wn) {
    int st = starts[b * Wn + s], cnt = counts[b * Wn + s];
    v = f4[(size_t)(b * Sn + st) * 192 + dc];
    if (cnt == 2) {
      float4 v2 = f4[(size_t)(b * Sn + st + 1) * 192 + dc];
      v.x = (v.x + v2.x) * 0.5f; v.y = (v.y + v2.y) * 0.5f;
      v.z = (v.z + v2.z) * 0.5f; v.w = (v.w + v2.w) * 0.5f;
    }
  } else {
    v = f4[(size_t)(b * Sn + s) * 192 + dc];
  }
  ushort4 o;
  o.x = f2bf(v.x); o.y = f2bf(v.y); o.z = f2bf(v.z); o.w = f2bf(v.w);
  ((ushort4*)f0p)[(size_t)(b * Sn + s) * 192 + dc] = o;
}

// ---------------------------------------------------------------------------
// xp GEMM: A = f0p [32768][768] bf16, B = wih [3072][768] bf16 (rows = gate)
// out: xp[d][t][b][1536] bf16,  value = A@B^T + biasc
__global__ void gemm_xp(const unsigned short* __restrict__ A, const unsigned short* __restrict__ Bw,
                        const float* __restrict__ biasc, unsigned short* __restrict__ xp) {
  __shared__ __align__(16) unsigned short As[128 * 32];
  __shared__ __align__(16) unsigned short Bs[128 * 32];
  int tid = threadIdx.x, w = tid >> 6, l = tid & 63, lr = l & 15, lq = l >> 4;
  int mBase = blockIdx.x * 128, nBase = blockIdx.y * 128;
  int mw = (w & 1) * 64, nw = (w >> 1) * 64;
  f32x4 acc[4][4];
#pragma unroll
  for (int mt = 0; mt < 4; ++mt)
#pragma unroll
    for (int nt = 0; nt < 4; ++nt) acc[mt][nt] = (f32x4){0.f, 0.f, 0.f, 0.f};

  for (int kb = 0; kb < 24; ++kb) {
    int k0 = kb * 32;
#pragma unroll
    for (int j = 0; j < 2; ++j) {
      int g = j * 256 + tid;
      int row = g >> 2, kc = (g & 3) * 8;
      GLL16(A + (size_t)(mBase + row) * 768 + k0 + kc, (char*)As + (j * 256 + w * 64) * 16);
      GLL16(Bw + (size_t)(nBase + row) * 768 + k0 + kc, (char*)Bs + (j * 256 + w * 64) * 16);
    }
    __syncthreads();
    short8 af[4], bfv[4];
#pragma unroll
    for (int mt = 0; mt < 4; ++mt) af[mt] = *(const short8*)&As[(mw + mt * 16 + lr) * 32 + lq * 8];
#pragma unroll
    for (int nt = 0; nt < 4; ++nt) bfv[nt] = *(const short8*)&Bs[(nw + nt * 16 + lr) * 32 + lq * 8];
#pragma unroll
    for (int mt = 0; mt < 4; ++mt)
#pragma unroll
      for (int nt = 0; nt < 4; ++nt)
        acc[mt][nt] = __builtin_amdgcn_mfma_f32_16x16x32_bf16(af[mt], bfv[nt], acc[mt][nt], 0, 0, 0);
    __syncthreads();
  }
  // epilogue: +bias, scatter to xp[d][t][b][g]
#pragma unroll
  for (int nt = 0; nt < 4; ++nt) {
    int n = nBase + nw + nt * 16 + lr;
    float bias = biasc[n];
    int d = (n >= 1536) ? 1 : 0;
    int gI = n - d * 1536;
#pragma unroll
    for (int mt = 0; mt < 4; ++mt) {
      int mrow = mBase + mw + mt * 16 + lq * 4;
#pragma unroll
      for (int r = 0; r < 4; ++r) {
        int m = mrow + r;
        int t = m & 511, b = m >> 9;
        xp[((size_t)((d * Sn + t) * Bn + b)) * 1536 + gI] = f2bf(acc[mt][nt][r] + bias);
      }
    }
  }
}

// ---------------------------------------------------------------------------
// Recurrence. 64 wgs; clique k = bid&7 (dir=k>>2, btile=k&3), member j=bid>>3
// (chunk), j>=6 exits. Agent mailbox htag[dir][slot][b:64][h:384] u32 =
// (tag<<16)|bf16 (V8, always written). FAST region htagF[xcd][slot][16][384]
// (local b-rows) via sc0/L2, engaged only when the clique verified
// single-XCD AND won the per-XCD claim. Consumers: FAST spin w/ timeout ->
// latch to agent path.
__global__ void __launch_bounds__(256, 1)
recur_kernel(const unsigned short* __restrict__ whh,   // [2][1536][384] bf16
             const unsigned short* __restrict__ xp,    // [2][512][64][1536] bf16
             unsigned short* __restrict__ h_all,       // [64][512][768] bf16
             unsigned int* __restrict__ htag,          // [2][2][64][384] u32 (agent)
             unsigned int* __restrict__ htagF,         // [8][2][16][384] u32 (sc0)
             unsigned int* __restrict__ xcdtab) {      // [64] ids | [64..127] ready | [128..135] claim
  int bid = blockIdx.x;
  int k = bid & 7, j = bid >> 3;
  if (j >= NCK) return;
  int dir = k >> 2, btile = k & 3, chunk = j;
  int tid = threadIdx.x, w = tid >> 6, l = tid & 63, lr = l & 15, lq = l >> 4;
  int hwb = chunk * 64 + w * 16;            // wave's h-row base (within dir)
  int pr = tid >> 4, pk = tid & 15;         // payload share: row 0..15, lane-in-row 0..15

  // ---- placement handshake (tid0) + per-XCD region claim ----
  unsigned int xcdr;
  asm volatile("s_getreg_b32 %0, hwreg(HW_REG_XCC_ID)" : "=s"(xcdr));
  int myx = (int)(xcdr & 7u);
  __shared__ int sh_fast;
  if (tid == 0) {
    __hip_atomic_store(&xcdtab[k * 8 + chunk], (unsigned)(myx | 0x10),
                       __ATOMIC_RELAXED, __HIP_MEMORY_SCOPE_AGENT);
    unsigned int first = 0; bool una = true;
    for (int j2 = 0; j2 < NCK; ++j2) {
      unsigned int u;
      while (!(u = __hip_atomic_load(&xcdtab[k * 8 + j2], __ATOMIC_RELAXED,
                                     __HIP_MEMORY_SCOPE_AGENT)))
        __builtin_amdgcn_s_sleep(1);
      if (j2 == 0) first = u; else una = una && (u == first);
    }
    int f = 0;
    if (una) {
      if (chunk == 0) {
        unsigned int exp0 = 0;
        __hip_atomic_compare_exchange_strong(&xcdtab[128 + myx], &exp0, (unsigned)(k + 1),
            __ATOMIC_RELAXED, __ATOMIC_RELAXED, __HIP_MEMORY_SCOPE_AGENT);
      }
      unsigned int cl;
      while (!(cl = __hip_atomic_load(&xcdtab[128 + myx], __ATOMIC_RELAXED,
                                      __HIP_MEMORY_SCOPE_AGENT)))
        __builtin_amdgcn_s_sleep(1);
      f = (cl == (unsigned)(k + 1)) ? 1 : 0;
    }
    sh_fast = f;
  }
  __syncthreads();
  const bool fast = (sh_fast != 0);
  unsigned int* regF = htagF + (size_t)myx * REGW;

  // FAST: scrub WHOLE region x in L2-x (masks any stale IC/L2 content from
  // prior launches; write-allocate pulls+overwrites), drain, ready-barrier.
  if (fast) {
    u32x4 z4 = (u32x4){0u, 0u, 0u, 0u};
    unsigned int* p0 = regF + tid * 48;
#pragma unroll
    for (int i = 0; i < 12; ++i)
      asm volatile("global_store_dwordx4 %0, %1, off sc0"
                   :: "v"(p0 + i * 4), "v"(z4) : "memory");
    asm volatile("s_waitcnt vmcnt(0)" ::: "memory");
    __syncthreads();
    if (tid == 0) {
      __hip_atomic_store(&xcdtab[64 + k * 8 + chunk], 1u, __ATOMIC_RELAXED,
                         __HIP_MEMORY_SCOPE_AGENT);
      for (int j2 = 0; j2 < NCK; ++j2)
        while (!__hip_atomic_load(&xcdtab[64 + k * 8 + j2], __ATOMIC_RELAXED,
                                  __HIP_MEMORY_SCOPE_AGENT))
          __builtin_amdgcn_s_sleep(1);
    }
    __syncthreads();
  }

  // double-buffered dedup stage: 2 x 12.25 KB; ONE barrier per step
  __shared__ __align__(16) unsigned int hlds[2][16 * 196];

  // permanent B-frags: whh[dir][q*384 + hwb + lr][kf*32 + lq*8 .. +8]
  short8 bfr[4][12];
#pragma unroll
  for (int q = 0; q < 4; ++q)
#pragma unroll
    for (int kf = 0; kf < 12; ++kf)
      bfr[q][kf] = *(const short8*)&whh[((size_t)dir * 1536 + q * 384 + hwb + lr) * 384 + kf * 32 + lq * 8];

  // xp prefetch: raw ushort regs, folded in AFTER the MFMA
  auto ldxp = [&](int tt, unsigned short* dst) {
#pragma unroll
    for (int q = 0; q < 4; ++q)
#pragma unroll
      for (int r = 0; r < 4; ++r) {
        int b = btile * 16 + lq * 4 + r;
        dst[q * 4 + r] = xp[((size_t)((dir * Sn + tt) * Bn + b)) * 1536 + q * 384 + hwb + lr];
      }
  };
  unsigned short xcur[16], xnxt[16];
  ldxp(dir ? (Sn - 1) : 0, xcur);

  f32x4 c0 = (f32x4){0.f, 0.f, 0.f, 0.f};
  bool fastc = fast;                         // consumer-side latch

  for (int it = 0; it < Sn; ++it) {
    int t = dir ? (Sn - 1 - it) : it;
    int tn = (it + 1 < Sn) ? (dir ? (Sn - 2 - it) : (it + 1)) : t;
    ldxp(tn, xnxt);                         // issued now, awaited at loop end

    f32x4 acc[4];
#pragma unroll
    for (int q = 0; q < 4; ++q) acc[q] = (f32x4){0.f, 0.f, 0.f, 0.f};

    if (it > 0) {
      const unsigned int expT = (unsigned int)it;
      int slot = (it - 1) & 1;
      unsigned long long v[12];
      bool have = false;
      if (fastc) {                          // FAST: sc0/L2 spin, bounded
        const unsigned long long* srowF = (const unsigned long long*)
            (regF + (size_t)slot * 6144 + (size_t)pr * 384);
        const void* sp = (const void*)(srowF + pk);
        int rounds = 0;
        while (true) {
          unsigned long long a0, a1, a2, a3, a4, a5, a6, a7, a8, a9, a10, a11;
          asm volatile(
            "global_load_dwordx2 %0,  %12, off sc0\n\t"
            "global_load_dwordx2 %1,  %12, off offset:128 sc0\n\t"
            "global_load_dwordx2 %2,  %12, off offset:256 sc0\n\t"
            "global_load_dwordx2 %3,  %12, off offset:384 sc0\n\t"
            "global_load_dwordx2 %4,  %12, off offset:512 sc0\n\t"
            "global_load_dwordx2 %5,  %12, off offset:640 sc0\n\t"
            "global_load_dwordx2 %6,  %12, off offset:768 sc0\n\t"
            "global_load_dwordx2 %7,  %12, off offset:896 sc0\n\t"
            "global_load_dwordx2 %8,  %12, off offset:1024 sc0\n\t"
            "global_load_dwordx2 %9,  %12, off offset:1152 sc0\n\t"
            "global_load_dwordx2 %10, %12, off offset:1280 sc0\n\t"
            "global_load_dwordx2 %11, %12, off offset:1408 sc0\n\t"
            "s_waitcnt vmcnt(0)"
            : "=&v"(a0), "=&v"(a1), "=&v"(a2), "=&v"(a3), "=&v"(a4), "=&v"(a5),
              "=&v"(a6), "=&v"(a7), "=&v"(a8), "=&v"(a9), "=&v"(a10), "=&v"(a11)
            : "v"(sp)
            : "memory");
          v[0] = a0; v[1] = a1; v[2] = a2; v[3] = a3; v[4] = a4; v[5] = a5;
          v[6] = a6; v[7] = a7; v[8] = a8; v[9] = a9; v[10] = a10; v[11] = a11;
          bool ok = true;
#pragma unroll
          for (int i = 0; i < 12; ++i)
            ok &= (((unsigned int)(v[i] >> 16) & 0xffffu) == expT) &
                  ((unsigned int)(v[i] >> 48) == expT);
          if (__all((int)ok)) { have = true; break; }
          if (++rounds > 4096) { fastc = false; break; }   // latch to agent
          __builtin_amdgcn_s_sleep(1);
        }
      }
      if (!have) {                          // V8 agent/IC path (always live)
        const unsigned long long* srow = (const unsigned long long*)
            (htag + (size_t)(dir * 2 + slot) * 64 * 384 + (size_t)(btile * 16 + pr) * 384);
        while (true) {
          bool ok = true;
#pragma unroll
          for (int i = 0; i < 12; ++i) {
            unsigned long long x = __hip_atomic_load(&srow[pk + 16 * i],
                                     __ATOMIC_RELAXED, __HIP_MEMORY_SCOPE_AGENT);
            v[i] = x;
            ok &= (((unsigned int)(x >> 16) & 0xffffu) == expT) &
                  ((unsigned int)(x >> 48) == expT);
          }
          if (__all((int)ok)) break;
          __builtin_amdgcn_s_sleep(1);
        }
      }
      // dedup into LDS buf[it&1], XOR-swizzled (word ^ ((row&7)<<2))
      unsigned int* dst = hlds[it & 1];
#pragma unroll
      for (int i = 0; i < 12; ++i)
        dst[pr * 196 + ((pk + 16 * i) ^ ((pr & 7) << 2))] =
            ((unsigned int)v[i] & 0xffffu) |
            (((unsigned int)(v[i] >> 32) & 0xffffu) << 16);
      __syncthreads();                      // the ONLY barrier per step
      // A-frags from LDS (same swizzle), MFMA over 12 k-tiles x 4 gates
      const char* src = (const char*)hlds[it & 1];
#pragma unroll
      for (int kf = 0; kf < 12; ++kf) {
        short8 a = *(const short8*)(src + lr * 784 +
                                    ((kf * 64 + lq * 16) ^ ((lr & 7) << 4)));
#pragma unroll
        for (int q = 0; q < 4; ++q)
          acc[q] = __builtin_amdgcn_mfma_f32_16x16x32_bf16(a, bfr[q][kf], acc[q], 0, 0, 0);
      }
    }

    // elementwise LSTM cell (xp folded here) + dual publish (never waits)
    unsigned int outTag = (unsigned int)(it + 1) << 16;
    int oslot = it & 1;
    unsigned int* obase = htag + (size_t)(dir * 2 + oslot) * 64 * 384;
    unsigned int* obF = regF + (size_t)oslot * 6144;
    unsigned short hb16v[4];
#pragma unroll
    for (int r = 0; r < 4; ++r) {
      float iv = sigm(acc[0][r] + bf2f(xcur[0 * 4 + r]));
      float fv = sigm(acc[1][r] + bf2f(xcur[1 * 4 + r]));
      float gv = tanhft(acc[2][r] + bf2f(xcur[2 * 4 + r]));
      float ov = sigm(acc[3][r] + bf2f(xcur[3 * 4 + r]));
      float cf = fv * c0[r] + iv * gv;
      c0[r] = cf;
      float hv = ov * tanhft(cf);
      hb16v[r] = f2bf(hv);
      unsigned int val = outTag | hb16v[r];
      if (fast) {                           // sc0 copy first: FAST consumers unblock
        unsigned int* pF = obF + (size_t)(lq * 4 + r) * 384 + hwb + lr;
        asm volatile("global_store_dword %0, %1, off sc0" :: "v"(pF), "v"(val) : "memory");
      }
      int b = btile * 16 + lq * 4 + r;
      __hip_atomic_store(&obase[(size_t)b * 384 + hwb + lr], val,
                         __ATOMIC_RELAXED, __HIP_MEMORY_SCOPE_AGENT);
    }
#pragma unroll
    for (int r = 0; r < 4; ++r) {           // plain copy for gemm_out (after publish)
      int b = btile * 16 + lq * 4 + r;
      h_all[((size_t)b * Sn + t) * 768 + dir * Hn + hwb + lr] = hb16v[r];
    }
#pragma unroll
    for (int i = 0; i < 16; ++i) xcur[i] = xnxt[i];   // xnxt wait lands HERE
  }
}

// ---------------------------------------------------------------------------
// out GEMM: A = h_all [32768][768] bf16, B = wlin [425][768] bf16
// out[m][n] fp32 = A@B^T + blin   (n predicated < 425)
__global__ void gemm_out(const unsigned short* __restrict__ A, const unsigned short* __restrict__ Bw,
                         const float* __restrict__ blin, float* __restrict__ out) {
  __shared__ __align__(16) unsigned short As[128 * 32];
  __shared__ __align__(16) unsigned short Bs[128 * 32];
  int tid = threadIdx.x, w = tid >> 6, l = tid & 63, lr = l & 15, lq = l >> 4;
  int mBase = blockIdx.x * 128, nBase = blockIdx.y * 128;
  int mw = (w & 1) * 64, nw = (w >> 1) * 64;
  f32x4 acc[4][4];
#pragma unroll
  for (int mt = 0; mt < 4; ++mt)
#pragma unroll
    for (int nt = 0; nt < 4; ++nt) acc[mt][nt] = (f32x4){0.f, 0.f, 0.f, 0.f};

  for (int kb = 0; kb < 24; ++kb) {
    int k0 = kb * 32;
#pragma unroll
    for (int j = 0; j < 2; ++j) {
      int g = j * 256 + tid;
      int row = g >> 2, kc = (g & 3) * 8;
      int nr = nBase + row; if (nr > Cn - 1) nr = Cn - 1;   // clamp: Wlin has 425 rows
      GLL16(A + (size_t)(mBase + row) * 768 + k0 + kc, (char*)As + (j * 256 + w * 64) * 16);
      GLL16(Bw + (size_t)nr * 768 + k0 + kc, (char*)Bs + (j * 256 + w * 64) * 16);
    }
    __syncthreads();
    short8 af[4], bfv[4];
#pragma unroll
    for (int mt = 0; mt < 4; ++mt) af[mt] = *(const short8*)&As[(mw + mt * 16 + lr) * 32 + lq * 8];
#pragma unroll
    for (int nt = 0; nt < 4; ++nt) bfv[nt] = *(const short8*)&Bs[(nw + nt * 16 + lr) * 32 + lq * 8];
#pragma unroll
    for (int mt = 0; mt < 4; ++mt)
#pragma unroll
      for (int nt = 0; nt < 4; ++nt)
        acc[mt][nt] = __builtin_amdgcn_mfma_f32_16x16x32_bf16(af[mt], bfv[nt], acc[mt][nt], 0, 0, 0);
    __syncthreads();
  }
#pragma unroll
  for (int nt = 0; nt < 4; ++nt) {
    int n = nBase + nw + nt * 16 + lr;
    if (n < Cn) {
      float bias = blin[n];
#pragma unroll
      for (int mt = 0; mt < 4; ++mt) {
        int mrow = mBase + mw + mt * 16 + lq * 4;
#pragma unroll
        for (int r = 0; r < 4; ++r) {
          int m = mrow + r;
          out[(size_t)m * Cn + n] = acc[mt][nt][r] + bias;
        }
      }
    }
  }
}

// ---------------------------------------------------------------------------
extern "C" void kernel_launch(void* const* d_in, const int* in_sizes, int n_in,
                              void* d_out, int out_size, void* d_ws, size_t ws_size,
                              hipStream_t stream) {
  (void)in_sizes; (void)n_in; (void)out_size;
  const float* f0     = (const float*)d_in[0];
  const int*   counts = (const int*)  d_in[1];
  const float* Wih_f  = (const float*)d_in[2];
  const float* Whh_f  = (const float*)d_in[3];
  const float* bih_f  = (const float*)d_in[4];
  const float* bhh_f  = (const float*)d_in[5];
  const float* Wih_b  = (const float*)d_in[6];
  const float* Whh_b  = (const float*)d_in[7];
  const float* bih_b  = (const float*)d_in[8];
  const float* bhh_b  = (const float*)d_in[9];
  const float* Wlin   = (const float*)d_in[10];
  const float* blin   = (const float*)d_in[11];
  float* out = (float*)d_out;

  char* ws = (char*)d_ws;
  size_t o = 0;
  auto alloc = [&](size_t bytes) { size_t cur = o; o += (bytes + 255) & ~(size_t)255; return cur; };
  size_t o_f0p    = alloc((size_t)Bn * Sn * Dn * 2);        // 50.3 MB (f0p; reused as h_all)
  size_t o_xp     = alloc((size_t)2 * Sn * Bn * G4H * 2);   // 201.3 MB
  size_t o_wih    = alloc((size_t)3072 * 768 * 2);
  size_t o_whh    = alloc((size_t)2 * 1536 * 384 * 2);
  size_t o_wlin   = alloc((size_t)Cn * 768 * 2);
  size_t o_bias   = alloc((size_t)3072 * 4);
  size_t o_starts = alloc((size_t)Bn * Wn * 4);
  size_t o_htag   = alloc((size_t)2 * 2 * 64 * 384 * 4);    // 786 KB agent mailbox
  size_t o_xcds   = alloc((size_t)160 * 4);                 // contiguous after htag
  size_t o_htagF  = alloc((size_t)8 * REGW * 4);            // 393 KB FAST regions
  if (o > ws_size) return;  // ~249 MiB of workspace

  unsigned short* f0p   = (unsigned short*)(ws + o_f0p);
  unsigned short* h_all = (unsigned short*)(ws + o_f0p);    // overlay: f0p dead after gemm_xp
  unsigned short* xp    = (unsigned short*)(ws + o_xp);
  unsigned short* wih   = (unsigned short*)(ws + o_wih);
  unsigned short* whh   = (unsigned short*)(ws + o_whh);
  unsigned short* wlin  = (unsigned short*)(ws + o_wlin);
  float*          biasc = (float*)(ws + o_bias);
  int*            starts= (int*)(ws + o_starts);
  unsigned int*   htag  = (unsigned int*)(ws + o_htag);
  unsigned int*   xcdtab= (unsigned int*)(ws + o_xcds);
  unsigned int*   htagF = (unsigned int*)(ws + o_htagF);

  {
    int nwords = 2 * 2 * 64 * 384 + 160;                    // htag + xcdtab (contiguous)
    zero_comm<<<(nwords + 255) / 256, 256, 0, stream>>>(htag, nwords);
  }
  scan_starts<<<Bn, 256, 0, stream>>>(counts, starts);
  {
    int total = 3072 * 768 + 2 * 1536 * 384 + Cn * 768 + 3072;
    prep_cast<<<(total + 255) / 256, 256, 0, stream>>>(Wih_f, Wih_b, Whh_f, Whh_b, Wlin,
                                                       bih_f, bhh_f, bih_b, bhh_b,
                                                       wih, whh, wlin, biasc);
  }
  pool_kernel<<<(Bn * Sn * 192) / 256, 256, 0, stream>>>(f0, counts, starts, f0p);
  gemm_xp<<<dim3(256, 24), 256, 0, stream>>>(f0p, wih, biasc, xp);
  recur_kernel<<<64, 256, 0, stream>>>(whh, xp, h_all, htag, htagF, xcdtab);
  gemm_out<<<dim3(256, 4), 256, 0, stream>>>(h_all, wlin, blin, out);
}

// Round 5
// 2163.065 us; speedup vs baseline: 3.2104x; 3.2104x over previous
//
#include <hip/hip_runtime.h>
#include <stdint.h>

// ---------------------------------------------------------------------------
// LSTMSupertaggingModel: segment-mean-pool -> BiLSTM(H=384) -> Linear(C=425)
// B=64, S=512, D=768, W=256, H=384, C=425
//
// V11 = V8 backbone + XCD-local FAST exchange v2 (atomic handshake):
//  - V10 post-mortem: FETCH 397->153MB proved FAST engaged, but sc0 plain
//    loads do NOT bypass L1 -> consumer progressed only on natural L1
//    eviction (~33k cy/step). And the LDS XOR swizzle was wrong (stride
//    196 = 4 words mod 32; XOR (pr&7)<<2 made rows r,r+4,r+8,r+12 collide:
//    7.06M -> 18.8M conflicts). Both reverted/replaced.
//  - FAST v2: atomics execute at the TCC (L2), never in L1 -> L1-proof.
//    Producer: sc0 payload stores -> vmcnt(0) -> lane0 atomic_add(+1)
//    sentinel (per producer wave, per slot). Consumer: spins atomic_add(0)
//    (return-old, sc0 flag) on 24 sentinels; then ONE plain-sc0 payload
//    round, L1-fresh via a 4-SLOT RING (same addr re-read every 4 steps,
//    ~114KB intervening traffic >> 32KB L1). Tags stay ground truth: stale
//    wave redoes its share on the agent path (always dual-published).
//  - All V10 safety nets kept: disjoint per-XCD region (claimed by CAS,
//    scrubbed through L2-x at claim -> cross-launch sound), unanimity
//    check, sentinel timeout latch, agent path unconditional.
//  - R5 lesson: Whh/dir = 1.18MB > CU register file -> cross-CU exchange
//    is structural; the game is exchange LATENCY.
// ---------------------------------------------------------------------------

typedef __attribute__((ext_vector_type(8))) short short8;
typedef __attribute__((ext_vector_type(4))) float f32x4;
typedef __attribute__((ext_vector_type(4))) unsigned int u32x4;

static constexpr int Bn = 64, Sn = 512, Dn = 768, Wn = 256, Hn = 384, Cn = 425;
static constexpr int G4H = 4 * Hn;          // 1536
static constexpr int NBT = 4;               // batch tiles of 16
static constexpr int NCK = 6;               // h-chunks of 64 rows per dir
static constexpr int NSLOT = 4;             // FAST payload ring depth
static constexpr int SLOTW = 16 * 384;      // 6144 words per FAST slot
static constexpr int SENT_BASE = NSLOT * SLOTW;       // 24576
static constexpr int REGW = SENT_BASE + NSLOT * 64;   // 24832 words per region

__device__ __forceinline__ unsigned short f2bf(float f) {
  unsigned int u = __float_as_uint(f);
  u += 0x7FFFu + ((u >> 16) & 1u);          // round-to-nearest-even
  return (unsigned short)(u >> 16);
}
__device__ __forceinline__ float bf2f(unsigned short h) {
  return __uint_as_float(((unsigned int)h) << 16);
}
__device__ __forceinline__ float sigm(float x)  { return 1.f / (1.f + __expf(-x)); }
__device__ __forceinline__ float tanhft(float x){ return 1.f - 2.f / (__expf(2.f * x) + 1.f); }

// async global->LDS, 16B per lane; LDS dest = wave-uniform base + lane*16
#define GLL16(gp, lp) __builtin_amdgcn_global_load_lds( \
  (const __attribute__((address_space(1))) unsigned int*)(gp), \
  (__attribute__((address_space(3))) unsigned int*)(lp), 16, 0, 0)

// ---------------------------------------------------------------------------
// zero comm region through the UC/atomic path (visible to agent-scope loads)
__global__ void zero_comm(unsigned int* p, int nwords) {
  int i = blockIdx.x * 256 + threadIdx.x;
  if (i < nwords)
    __hip_atomic_store(&p[i], 0u, __ATOMIC_RELAXED, __HIP_MEMORY_SCOPE_AGENT);
}

// ---------------------------------------------------------------------------
__global__ void scan_starts(const int* __restrict__ counts, int* __restrict__ starts) {
  int b = blockIdx.x, j = threadIdx.x;      // 64 blocks x 256 threads
  __shared__ int sm[256];
  int c = counts[b * Wn + j];
  sm[j] = c;
  __syncthreads();
  for (int off = 1; off < 256; off <<= 1) {
    int v = (j >= off) ? sm[j - off] : 0;
    __syncthreads();
    sm[j] += v;
    __syncthreads();
  }
  starts[b * Wn + j] = sm[j] - c;           // exclusive
}

// ---------------------------------------------------------------------------
__global__ void prep_cast(const float* __restrict__ Wih_f, const float* __restrict__ Wih_b,
                          const float* __restrict__ Whh_f, const float* __restrict__ Whh_b,
                          const float* __restrict__ Wlin,
                          const float* __restrict__ bih_f, const float* __restrict__ bhh_f,
                          const float* __restrict__ bih_b, const float* __restrict__ bhh_b,
                          unsigned short* __restrict__ wih, unsigned short* __restrict__ whh,
                          unsigned short* __restrict__ wlin, float* __restrict__ biasc) {
  int i = blockIdx.x * 256 + threadIdx.x;
  const int T0 = 3072 * 768;                // Wih both dirs
  const int T1 = 2 * 1536 * 384;            // Whh both dirs
  const int T2 = Cn * 768;                  // Wlin
  const int T3 = 3072;                      // bias
  if (i < T0) {
    int n = i / 768, k = i - n * 768;
    float v = (n < 1536) ? Wih_f[n * 768 + k] : Wih_b[(n - 1536) * 768 + k];
    wih[i] = f2bf(v);
  } else if (i < T0 + T1) {
    int j = i - T0;
    float v = (j < 1536 * 384) ? Whh_f[j] : Whh_b[j - 1536 * 384];
    whh[j] = f2bf(v);
  } else if (i < T0 + T1 + T2) {
    int j = i - T0 - T1;
    wlin[j] = f2bf(Wlin[j]);
  } else if (i < T0 + T1 + T2 + T3) {
    int n = i - T0 - T1 - T2;
    biasc[n] = (n < 1536) ? (bih_f[n] + bhh_f[n]) : (bih_b[n - 1536] + bhh_b[n - 1536]);
  }
}

// ---------------------------------------------------------------------------
// ragged segment mean: f0p[b*S+s][:] = s<W ? mean(f0[b, st..st+cnt)) : f0[b,s]
__global__ void pool_kernel(const float* __restrict__ f0, const int* __restrict__ counts,
                            const int* __restrict__ starts, unsigned short* __restrict__ f0p) {
  int idx = blockIdx.x * 256 + threadIdx.x;           // B*S*192 exact
  int dc = idx % 192;
  int rest = idx / 192;
  int s = rest & 511, b = rest >> 9;
  const float4* f4 = (const float4*)f0;
  float4 v;
  if (s < Wn) {
    int st = starts[b * Wn + s], cnt = counts[b * Wn + s];
    v = f4[(size_t)(b * Sn + st) * 192 + dc];
    if (cnt == 2) {
      float4 v2 = f4[(size_t)(b * Sn + st + 1) * 192 + dc];
      v.x = (v.x + v2.x) * 0.5f; v.y = (v.y + v2.y) * 0.5f;
      v.z = (v.z + v2.z) * 0.5f; v.w = (v.w + v2.w) * 0.5f;
    }
  } else {
    v = f4[(size_t)(b * Sn + s) * 192 + dc];
  }
  ushort4 o;
  o.x = f2bf(v.x); o.y = f2bf(v.y); o.z = f2bf(v.z); o.w = f2bf(v.w);
  ((ushort4*)f0p)[(size_t)(b * Sn + s) * 192 + dc] = o;
}

// ---------------------------------------------------------------------------
// xp GEMM: A = f0p [32768][768] bf16, B = wih [3072][768] bf16 (rows = gate)
// out: xp[d][t][b][1536] bf16,  value = A@B^T + biasc
__global__ void gemm_xp(const unsigned short* __restrict__ A, const unsigned short* __restrict__ Bw,
                        const float* __restrict__ biasc, unsigned short* __restrict__ xp) {
  __shared__ __align__(16) unsigned short As[128 * 32];
  __shared__ __align__(16) unsigned short Bs[128 * 32];
  int tid = threadIdx.x, w = tid >> 6, l = tid & 63, lr = l & 15, lq = l >> 4;
  int mBase = blockIdx.x * 128, nBase = blockIdx.y * 128;
  int mw = (w & 1) * 64, nw = (w >> 1) * 64;
  f32x4 acc[4][4];
#pragma unroll
  for (int mt = 0; mt < 4; ++mt)
#pragma unroll
    for (int nt = 0; nt < 4; ++nt) acc[mt][nt] = (f32x4){0.f, 0.f, 0.f, 0.f};

  for (int kb = 0; kb < 24; ++kb) {
    int k0 = kb * 32;
#pragma unroll
    for (int j = 0; j < 2; ++j) {
      int g = j * 256 + tid;
      int row = g >> 2, kc = (g & 3) * 8;
      GLL16(A + (size_t)(mBase + row) * 768 + k0 + kc, (char*)As + (j * 256 + w * 64) * 16);
      GLL16(Bw + (size_t)(nBase + row) * 768 + k0 + kc, (char*)Bs + (j * 256 + w * 64) * 16);
    }
    __syncthreads();
    short8 af[4], bfv[4];
#pragma unroll
    for (int mt = 0; mt < 4; ++mt) af[mt] = *(const short8*)&As[(mw + mt * 16 + lr) * 32 + lq * 8];
#pragma unroll
    for (int nt = 0; nt < 4; ++nt) bfv[nt] = *(const short8*)&Bs[(nw + nt * 16 + lr) * 32 + lq * 8];
#pragma unroll
    for (int mt = 0; mt < 4; ++mt)
#pragma unroll
      for (int nt = 0; nt < 4; ++nt)
        acc[mt][nt] = __builtin_amdgcn_mfma_f32_16x16x32_bf16(af[mt], bfv[nt], acc[mt][nt], 0, 0, 0);
    __syncthreads();
  }
  // epilogue: +bias, scatter to xp[d][t][b][g]
#pragma unroll
  for (int nt = 0; nt < 4; ++nt) {
    int n = nBase + nw + nt * 16 + lr;
    float bias = biasc[n];
    int d = (n >= 1536) ? 1 : 0;
    int gI = n - d * 1536;
#pragma unroll
    for (int mt = 0; mt < 4; ++mt) {
      int mrow = mBase + mw + mt * 16 + lq * 4;
#pragma unroll
      for (int r = 0; r < 4; ++r) {
        int m = mrow + r;
        int t = m & 511, b = m >> 9;
        xp[((size_t)((d * Sn + t) * Bn + b)) * 1536 + gI] = f2bf(acc[mt][nt][r] + bias);
      }
    }
  }
}

// ---------------------------------------------------------------------------
// Recurrence. 64 wgs; clique k = bid&7 (dir=k>>2, btile=k&3), member j=bid>>3
// (chunk), j>=6 exits. Agent mailbox htag[dir][slot][b:64][h:384] u32 =
// (tag<<16)|bf16 (V8, ALWAYS written). FAST region htagF[xcd]:
//   [0 .. 4*6144)  payload ring, 4 slots x [16 b][384 h] (sc0 stores/loads)
//   [24576 .. )    sentinels, 4 slots x 64 (atomic_add, executed at L2-x)
__global__ void __launch_bounds__(256, 1)
recur_kernel(const unsigned short* __restrict__ whh,   // [2][1536][384] bf16
             const unsigned short* __restrict__ xp,    // [2][512][64][1536] bf16
             unsigned short* __restrict__ h_all,       // [64][512][768] bf16
             unsigned int* __restrict__ htag,          // [2][2][64][384] u32 (agent)
             unsigned int* __restrict__ htagF,         // [8][REGW] u32 (L2-x only)
             unsigned int* __restrict__ xcdtab) {      // [64] ids | [64..127] ready | [128..135] claim
  int bid = blockIdx.x;
  int k = bid & 7, j = bid >> 3;
  if (j >= NCK) return;
  int dir = k >> 2, btile = k & 3, chunk = j;
  int tid = threadIdx.x, w = tid >> 6, l = tid & 63, lr = l & 15, lq = l >> 4;
  int hwb = chunk * 64 + w * 16;            // wave's h-row base (within dir)
  int pr = tid >> 4, pk = tid & 15;         // payload share: row 0..15, lane-in-row 0..15

  // ---- placement handshake (tid0) + per-XCD region claim ----
  unsigned int xcdr;
  asm volatile("s_getreg_b32 %0, hwreg(HW_REG_XCC_ID)" : "=s"(xcdr));
  int myx = (int)(xcdr & 7u);
  __shared__ int sh_fast;
  if (tid == 0) {
    __hip_atomic_store(&xcdtab[k * 8 + chunk], (unsigned)(myx | 0x10),
                       __ATOMIC_RELAXED, __HIP_MEMORY_SCOPE_AGENT);
    unsigned int first = 0; bool una = true;
    for (int j2 = 0; j2 < NCK; ++j2) {
      unsigned int u;
      while (!(u = __hip_atomic_load(&xcdtab[k * 8 + j2], __ATOMIC_RELAXED,
                                     __HIP_MEMORY_SCOPE_AGENT)))
        __builtin_amdgcn_s_sleep(1);
      if (j2 == 0) first = u; else una = una && (u == first);
    }
    int f = 0;
    if (una) {
      if (chunk == 0) {
        unsigned int exp0 = 0;
        __hip_atomic_compare_exchange_strong(&xcdtab[128 + myx], &exp0, (unsigned)(k + 1),
            __ATOMIC_RELAXED, __ATOMIC_RELAXED, __HIP_MEMORY_SCOPE_AGENT);
      }
      unsigned int cl;
      while (!(cl = __hip_atomic_load(&xcdtab[128 + myx], __ATOMIC_RELAXED,
                                      __HIP_MEMORY_SCOPE_AGENT)))
        __builtin_amdgcn_s_sleep(1);
      f = (cl == (unsigned)(k + 1)) ? 1 : 0;
    }
    sh_fast = f;
  }
  __syncthreads();
  const bool fast = (sh_fast != 0);
  unsigned int* regF = htagF + (size_t)myx * REGW;

  // FAST: scrub WHOLE region (payload + sentinels) through L2-x; any prior
  // launch's dirty lines for these addresses also live only in L2-x ->
  // single coherence point across launches. Drain, clique ready-barrier.
  if (fast) {
    u32x4 z4 = (u32x4){0u, 0u, 0u, 0u};
    for (int i = tid; i < REGW / 4; i += 256)
      asm volatile("global_store_dwordx4 %0, %1, off sc0"
                   :: "v"(regF + (size_t)i * 4), "v"(z4) : "memory");
    asm volatile("s_waitcnt vmcnt(0)" ::: "memory");
    __syncthreads();
    if (tid == 0) {
      __hip_atomic_store(&xcdtab[64 + k * 8 + chunk], 1u, __ATOMIC_RELAXED,
                         __HIP_MEMORY_SCOPE_AGENT);
      for (int j2 = 0; j2 < NCK; ++j2)
        while (!__hip_atomic_load(&xcdtab[64 + k * 8 + j2], __ATOMIC_RELAXED,
                                  __HIP_MEMORY_SCOPE_AGENT))
          __builtin_amdgcn_s_sleep(1);
    }
    __syncthreads();
  }

  // double-buffered dedup stage: 2 x 12.25 KB; ONE barrier per step
  __shared__ __align__(16) unsigned int hlds[2][16 * 196];

  // permanent B-frags: whh[dir][q*384 + hwb + lr][kf*32 + lq*8 .. +8]
  short8 bfr[4][12];
#pragma unroll
  for (int q = 0; q < 4; ++q)
#pragma unroll
    for (int kf = 0; kf < 12; ++kf)
      bfr[q][kf] = *(const short8*)&whh[((size_t)dir * 1536 + q * 384 + hwb + lr) * 384 + kf * 32 + lq * 8];

  // xp prefetch: raw ushort regs, folded in AFTER the MFMA
  auto ldxp = [&](int tt, unsigned short* dst) {
#pragma unroll
    for (int q = 0; q < 4; ++q)
#pragma unroll
      for (int r = 0; r < 4; ++r) {
        int b = btile * 16 + lq * 4 + r;
        dst[q * 4 + r] = xp[((size_t)((dir * Sn + tt) * Bn + b)) * 1536 + q * 384 + hwb + lr];
      }
  };
  unsigned short xcur[16], xnxt[16];
  ldxp(dir ? (Sn - 1) : 0, xcur);

  f32x4 c0 = (f32x4){0.f, 0.f, 0.f, 0.f};
  bool sentOK = fast;                        // sentinel-health latch

  for (int it = 0; it < Sn; ++it) {
    int t = dir ? (Sn - 1 - it) : it;
    int tn = (it + 1 < Sn) ? (dir ? (Sn - 2 - it) : (it + 1)) : t;
    ldxp(tn, xnxt);                         // issued now, awaited at loop end

    f32x4 acc[4];
#pragma unroll
    for (int q = 0; q < 4; ++q) acc[q] = (f32x4){0.f, 0.f, 0.f, 0.f};

    if (it > 0) {
      const unsigned int expT = (unsigned int)it;
      int slot = (it - 1) & 1;
      unsigned long long v[12];
      bool have = false;
      if (fast) {
        int p = it - 1;
        int slotF = p & 3;
        // 1) sentinel spin: atomics execute at L2-x -> L1-proof detection
        if (sentOK) {
          unsigned int expS = (unsigned)(p >> 2) + 1u;
          int li = (l < 24) ? l : 0;
          unsigned int* sp = regF + SENT_BASE + slotF * 64 + li;
          int got = (l < 24) ? 0 : 1;
          int rounds = 0;
          while (true) {
            if (!got) {
              unsigned int old;
              asm volatile("global_atomic_add %0, %1, %2, off sc0\n\t"
                           "s_waitcnt vmcnt(0)"
                           : "=&v"(old) : "v"(sp), "v"(0u) : "memory");
              got = (old >= expS) ? 1 : 0;
            }
            if (__all(got)) break;
            if (++rounds > 3000) { sentOK = false; break; }
          }
        }
        // 2) ONE payload round, plain sc0 loads. 4-slot ring => same addr
        //    last read 4 steps ago (~114KB L1 traffic since) -> L1-fresh.
        const unsigned long long* srowF = (const unsigned long long*)
            (regF + (size_t)slotF * SLOTW + (size_t)pr * 384);
        const void* sp2 = (const void*)(srowF + pk);
        unsigned long long a0, a1, a2, a3, a4, a5, a6, a7, a8, a9, a10, a11;
        asm volatile(
          "global_load_dwordx2 %0,  %12, off sc0\n\t"
          "global_load_dwordx2 %1,  %12, off offset:128 sc0\n\t"
          "global_load_dwordx2 %2,  %12, off offset:256 sc0\n\t"
          "global_load_dwordx2 %3,  %12, off offset:384 sc0\n\t"
          "global_load_dwordx2 %4,  %12, off offset:512 sc0\n\t"
          "global_load_dwordx2 %5,  %12, off offset:640 sc0\n\t"
          "global_load_dwordx2 %6,  %12, off offset:768 sc0\n\t"
          "global_load_dwordx2 %7,  %12, off offset:896 sc0\n\t"
          "global_load_dwordx2 %8,  %12, off offset:1024 sc0\n\t"
          "global_load_dwordx2 %9,  %12, off offset:1152 sc0\n\t"
          "global_load_dwordx2 %10, %12, off offset:1280 sc0\n\t"
          "global_load_dwordx2 %11, %12, off offset:1408 sc0\n\t"
          "s_waitcnt vmcnt(0)"
          : "=&v"(a0), "=&v"(a1), "=&v"(a2), "=&v"(a3), "=&v"(a4), "=&v"(a5),
            "=&v"(a6), "=&v"(a7), "=&v"(a8), "=&v"(a9), "=&v"(a10), "=&v"(a11)
          : "v"(sp2)
          : "memory");
        v[0] = a0; v[1] = a1; v[2] = a2; v[3] = a3; v[4] = a4; v[5] = a5;
        v[6] = a6; v[7] = a7; v[8] = a8; v[9] = a9; v[10] = a10; v[11] = a11;
        bool ok = true;
#pragma unroll
        for (int i = 0; i < 12; ++i)
          ok &= (((unsigned int)(v[i] >> 16) & 0xffffu) == expT) &
                ((unsigned int)(v[i] >> 48) == expT);
        have = __all((int)ok);
      }
      if (!have) {                          // V8 agent/IC path (always live)
        const unsigned long long* srow = (const unsigned long long*)
            (htag + (size_t)(dir * 2 + slot) * 64 * 384 + (size_t)(btile * 16 + pr) * 384);
        while (true) {
          bool ok = true;
#pragma unroll
          for (int i = 0; i < 12; ++i) {
            unsigned long long x = __hip_atomic_load(&srow[pk + 16 * i],
                                     __ATOMIC_RELAXED, __HIP_MEMORY_SCOPE_AGENT);
            v[i] = x;
            ok &= (((unsigned int)(x >> 16) & 0xffffu) == expT) &
                  ((unsigned int)(x >> 48) == expT);
          }
          if (__all((int)ok)) break;
          __builtin_amdgcn_s_sleep(1);
        }
      }
      // dedup into LDS buf[it&1] (V8 layout — swizzle reverted)
      unsigned int* dst = hlds[it & 1];
#pragma unroll
      for (int i = 0; i < 12; ++i)
        dst[pr * 196 + pk + 16 * i] = ((unsigned int)v[i] & 0xffffu) |
                                      (((unsigned int)(v[i] >> 32) & 0xffffu) << 16);
      __syncthreads();                      // the ONLY barrier per step
      // A-frags from LDS, MFMA over 12 k-tiles x 4 gates
      const char* src = (const char*)hlds[it & 1];
#pragma unroll
      for (int kf = 0; kf < 12; ++kf) {
        short8 a = *(const short8*)(src + lr * 784 + kf * 64 + lq * 16);
#pragma unroll
        for (int q = 0; q < 4; ++q)
          acc[q] = __builtin_amdgcn_mfma_f32_16x16x32_bf16(a, bfr[q][kf], acc[q], 0, 0, 0);
      }
    }

    // elementwise LSTM cell (xp folded here)
    unsigned int outTag = (unsigned int)(it + 1) << 16;
    unsigned short hb16v[4];
#pragma unroll
    for (int r = 0; r < 4; ++r) {
      float iv = sigm(acc[0][r] + bf2f(xcur[0 * 4 + r]));
      float fv = sigm(acc[1][r] + bf2f(xcur[1 * 4 + r]));
      float gv = tanhft(acc[2][r] + bf2f(xcur[2 * 4 + r]));
      float ov = sigm(acc[3][r] + bf2f(xcur[3 * 4 + r]));
      float cf = fv * c0[r] + iv * gv;
      c0[r] = cf;
      float hv = ov * tanhft(cf);
      hb16v[r] = f2bf(hv);
    }
    // FAST publish first: sc0 payload -> drain -> lane0 sentinel +1 (L2-x)
    if (fast) {
      int slotFo = it & 3;
      unsigned int* obF = regF + (size_t)slotFo * SLOTW;
#pragma unroll
      for (int r = 0; r < 4; ++r) {
        unsigned int val = outTag | hb16v[r];
        unsigned int* pF = obF + (size_t)(lq * 4 + r) * 384 + hwb + lr;
        asm volatile("global_store_dword %0, %1, off sc0" :: "v"(pF), "v"(val) : "memory");
      }
      asm volatile("s_waitcnt vmcnt(0)" ::: "memory");
      if (l == 0) {
        unsigned int* sp = regF + SENT_BASE + slotFo * 64 + chunk * 4 + w;
        asm volatile("global_atomic_add %0, %1, off" :: "v"(sp), "v"(1u) : "memory");
      }
    }
    // agent publish ALWAYS (liveness backbone)
    int oslot = it & 1;
    unsigned int* obase = htag + (size_t)(dir * 2 + oslot) * 64 * 384;
#pragma unroll
    for (int r = 0; r < 4; ++r) {
      int b = btile * 16 + lq * 4 + r;
      __hip_atomic_store(&obase[(size_t)b * 384 + hwb + lr], outTag | hb16v[r],
                         __ATOMIC_RELAXED, __HIP_MEMORY_SCOPE_AGENT);
    }
#pragma unroll
    for (int r = 0; r < 4; ++r) {           // plain copy for gemm_out (after publish)
      int b = btile * 16 + lq * 4 + r;
      h_all[((size_t)b * Sn + t) * 768 + dir * Hn + hwb + lr] = hb16v[r];
    }
#pragma unroll
    for (int i = 0; i < 16; ++i) xcur[i] = xnxt[i];   // xnxt wait lands HERE
  }
}

// ---------------------------------------------------------------------------
// out GEMM: A = h_all [32768][768] bf16, B = wlin [425][768] bf16
// out[m][n] fp32 = A@B^T + blin   (n predicated < 425)
__global__ void gemm_out(const unsigned short* __restrict__ A, const unsigned short* __restrict__ Bw,
                         const float* __restrict__ blin, float* __restrict__ out) {
  __shared__ __align__(16) unsigned short As[128 * 32];
  __shared__ __align__(16) unsigned short Bs[128 * 32];
  int tid = threadIdx.x, w = tid >> 6, l = tid & 63, lr = l & 15, lq = l >> 4;
  int mBase = blockIdx.x * 128, nBase = blockIdx.y * 128;
  int mw = (w & 1) * 64, nw = (w >> 1) * 64;
  f32x4 acc[4][4];
#pragma unroll
  for (int mt = 0; mt < 4; ++mt)
#pragma unroll
    for (int nt = 0; nt < 4; ++nt) acc[mt][nt] = (f32x4){0.f, 0.f, 0.f, 0.f};

  for (int kb = 0; kb < 24; ++kb) {
    int k0 = kb * 32;
#pragma unroll
    for (int j = 0; j < 2; ++j) {
      int g = j * 256 + tid;
      int row = g >> 2, kc = (g & 3) * 8;
      int nr = nBase + row; if (nr > Cn - 1) nr = Cn - 1;   // clamp: Wlin has 425 rows
      GLL16(A + (size_t)(mBase + row) * 768 + k0 + kc, (char*)As + (j * 256 + w * 64) * 16);
      GLL16(Bw + (size_t)nr * 768 + k0 + kc, (char*)Bs + (j * 256 + w * 64) * 16);
    }
    __syncthreads();
    short8 af[4], bfv[4];
#pragma unroll
    for (int mt = 0; mt < 4; ++mt) af[mt] = *(const short8*)&As[(mw + mt * 16 + lr) * 32 + lq * 8];
#pragma unroll
    for (int nt = 0; nt < 4; ++nt) bfv[nt] = *(const short8*)&Bs[(nw + nt * 16 + lr) * 32 + lq * 8];
#pragma unroll
    for (int mt = 0; mt < 4; ++mt)
#pragma unroll
      for (int nt = 0; nt < 4; ++nt)
        acc[mt][nt] = __builtin_amdgcn_mfma_f32_16x16x32_bf16(af[mt], bfv[nt], acc[mt][nt], 0, 0, 0);
    __syncthreads();
  }
#pragma unroll
  for (int nt = 0; nt < 4; ++nt) {
    int n = nBase + nw + nt * 16 + lr;
    if (n < Cn) {
      float bias = blin[n];
#pragma unroll
      for (int mt = 0; mt < 4; ++mt) {
        int mrow = mBase + mw + mt * 16 + lq * 4;
#pragma unroll
        for (int r = 0; r < 4; ++r) {
          int m = mrow + r;
          out[(size_t)m * Cn + n] = acc[mt][nt][r] + bias;
        }
      }
    }
  }
}

// ---------------------------------------------------------------------------
extern "C" void kernel_launch(void* const* d_in, const int* in_sizes, int n_in,
                              void* d_out, int out_size, void* d_ws, size_t ws_size,
                              hipStream_t stream) {
  (void)in_sizes; (void)n_in; (void)out_size;
  const float* f0     = (const float*)d_in[0];
  const int*   counts = (const int*)  d_in[1];
  const float* Wih_f  = (const float*)d_in[2];
  const float* Whh_f  = (const float*)d_in[3];
  const float* bih_f  = (const float*)d_in[4];
  const float* bhh_f  = (const float*)d_in[5];
  const float* Wih_b  = (const float*)d_in[6];
  const float* Whh_b  = (const float*)d_in[7];
  const float* bih_b  = (const float*)d_in[8];
  const float* bhh_b  = (const float*)d_in[9];
  const float* Wlin   = (const float*)d_in[10];
  const float* blin   = (const float*)d_in[11];
  float* out = (float*)d_out;

  char* ws = (char*)d_ws;
  size_t o = 0;
  auto alloc = [&](size_t bytes) { size_t cur = o; o += (bytes + 255) & ~(size_t)255; return cur; };
  size_t o_f0p    = alloc((size_t)Bn * Sn * Dn * 2);        // 50.3 MB (f0p; reused as h_all)
  size_t o_xp     = alloc((size_t)2 * Sn * Bn * G4H * 2);   // 201.3 MB
  size_t o_wih    = alloc((size_t)3072 * 768 * 2);
  size_t o_whh    = alloc((size_t)2 * 1536 * 384 * 2);
  size_t o_wlin   = alloc((size_t)Cn * 768 * 2);
  size_t o_bias   = alloc((size_t)3072 * 4);
  size_t o_starts = alloc((size_t)Bn * Wn * 4);
  size_t o_htag   = alloc((size_t)2 * 2 * 64 * 384 * 4);    // 384 KB agent mailbox
  size_t o_xcds   = alloc((size_t)160 * 4);                 // contiguous after htag
  size_t o_htagF  = alloc((size_t)8 * REGW * 4);            // 795 KB FAST regions
  if (o > ws_size) return;  // ~253 MiB of workspace

  unsigned short* f0p   = (unsigned short*)(ws + o_f0p);
  unsigned short* h_all = (unsigned short*)(ws + o_f0p);    // overlay: f0p dead after gemm_xp
  unsigned short* xp    = (unsigned short*)(ws + o_xp);
  unsigned short* wih   = (unsigned short*)(ws + o_wih);
  unsigned short* whh   = (unsigned short*)(ws + o_whh);
  unsigned short* wlin  = (unsigned short*)(ws + o_wlin);
  float*          biasc = (float*)(ws + o_bias);
  int*            starts= (int*)(ws + o_starts);
  unsigned int*   htag  = (unsigned int*)(ws + o_htag);
  unsigned int*   xcdtab= (unsigned int*)(ws + o_xcds);
  unsigned int*   htagF = (unsigned int*)(ws + o_htagF);

  {
    int nwords = 2 * 2 * 64 * 384 + 160;                    // htag + xcdtab (contiguous)
    zero_comm<<<(nwords + 255) / 256, 256, 0, stream>>>(htag, nwords);
  }
  scan_starts<<<Bn, 256, 0, stream>>>(counts, starts);
  {
    int total = 3072 * 768 + 2 * 1536 * 384 + Cn * 768 + 3072;
    prep_cast<<<(total + 255) / 256, 256, 0, stream>>>(Wih_f, Wih_b, Whh_f, Whh_b, Wlin,
                                                       bih_f, bhh_f, bih_b, bhh_b,
                                                       wih, whh, wlin, biasc);
  }
  pool_kernel<<<(Bn * Sn * 192) / 256, 256, 0, stream>>>(f0, counts, starts, f0p);
  gemm_xp<<<dim3(256, 24), 256, 0, stream>>>(f0p, wih, biasc, xp);
  recur_kernel<<<64, 256, 0, stream>>>(whh, xp, h_all, htag, htagF, xcdtab);
  gemm_out<<<dim3(256, 4), 256, 0, stream>>>(h_all, wlin, blin, out);
}

// Round 7
// 1902.348 us; speedup vs baseline: 3.6504x; 1.1371x over previous
//
#include <hip/hip_runtime.h>
#include <stdint.h>

// ---------------------------------------------------------------------------
// LSTMSupertaggingModel: segment-mean-pool -> BiLSTM(H=384) -> Linear(C=425)
// B=64, S=512, D=768, W=256, H=384, C=425
//
// V13 = V8 recurrence (proven 1405us) FUSED with the xp GEMM so the ~300us
// of gemm_xp hides behind the latency-bound recurrence:
//  - one kernel, 6192 blocks: bid<48 = recur wgs (dispatched first, each
//    pins a CU); bid>=48 = gemm tiles on the remaining ~208 CUs.
//  - f0p/h_all rows reordered to [s*64+b]: an M-tile = 2 timesteps x 64
//    batch -> tile completion aligns with recur consumption AND the
//    f0p<->h_all overlay becomes row-aligned (h_all(t) clobbers only
//    f0p(t), whose readers are exactly the gated tiles).
//  - publication: gemm stores xp via u16 AGENT atomic stores (write-through
//    to IC; same instr count as the previous scalar u16 stores), vmcnt(0),
//    then one per-wg atomicAdd on gcnt[mtile>>3] (32 groups of 8 mtiles,
//    target 8*24=192). recur gates on the group counter once per 16 steps.
//  - priority order: tiles from both t-ends (mt = r<24 ? q : 255-q) so
//    dir0/grp0 and dir1/grp31 finish in the first ~25-30us.
//  - deadlock-free: gemm blocks have no deps; 48 recur wgs can't exhaust
//    256 CUs; gate spin bounded by guaranteed gemm completion.
//  - exchange-latency line CLOSED after V9-V12: V8's agent mailbox
//    (~6600cy/step) is robustly 1.4-1.5ms; FAST/L2 variants all lost.
// ---------------------------------------------------------------------------

typedef __attribute__((ext_vector_type(8))) short short8;
typedef __attribute__((ext_vector_type(4))) float f32x4;

static constexpr int Bn = 64, Sn = 512, Dn = 768, Wn = 256, Hn = 384, Cn = 425;
static constexpr int G4H = 4 * Hn;          // 1536
static constexpr int NBT = 4;               // batch tiles of 16
static constexpr int NCK = 6;               // h-chunks of 64 rows per dir
static constexpr int NRWG = 2 * NBT * NCK;  // 48 recur wgs

__device__ __forceinline__ unsigned short f2bf(float f) {
  unsigned int u = __float_as_uint(f);
  u += 0x7FFFu + ((u >> 16) & 1u);          // round-to-nearest-even
  return (unsigned short)(u >> 16);
}
__device__ __forceinline__ float bf2f(unsigned short h) {
  return __uint_as_float(((unsigned int)h) << 16);
}
__device__ __forceinline__ float sigm(float x)  { return 1.f / (1.f + __expf(-x)); }
__device__ __forceinline__ float tanhft(float x){ return 1.f - 2.f / (__expf(2.f * x) + 1.f); }

// async global->LDS, 16B per lane; LDS dest = wave-uniform base + lane*16
#define GLL16(gp, lp) __builtin_amdgcn_global_load_lds( \
  (const __attribute__((address_space(1))) unsigned int*)(gp), \
  (__attribute__((address_space(3))) unsigned int*)(lp), 16, 0, 0)

// ---------------------------------------------------------------------------
// zero comm region through the UC/atomic path (visible to agent-scope loads)
__global__ void zero_comm(unsigned int* p, int nwords) {
  int i = blockIdx.x * 256 + threadIdx.x;
  if (i < nwords)
    __hip_atomic_store(&p[i], 0u, __ATOMIC_RELAXED, __HIP_MEMORY_SCOPE_AGENT);
}

// ---------------------------------------------------------------------------
__global__ void scan_starts(const int* __restrict__ counts, int* __restrict__ starts) {
  int b = blockIdx.x, j = threadIdx.x;      // 64 blocks x 256 threads
  __shared__ int sm[256];
  int c = counts[b * Wn + j];
  sm[j] = c;
  __syncthreads();
  for (int off = 1; off < 256; off <<= 1) {
    int v = (j >= off) ? sm[j - off] : 0;
    __syncthreads();
    sm[j] += v;
    __syncthreads();
  }
  starts[b * Wn + j] = sm[j] - c;           // exclusive
}

// ---------------------------------------------------------------------------
__global__ void prep_cast(const float* __restrict__ Wih_f, const float* __restrict__ Wih_b,
                          const float* __restrict__ Whh_f, const float* __restrict__ Whh_b,
                          const float* __restrict__ Wlin,
                          const float* __restrict__ bih_f, const float* __restrict__ bhh_f,
                          const float* __restrict__ bih_b, const float* __restrict__ bhh_b,
                          unsigned short* __restrict__ wih, unsigned short* __restrict__ whh,
                          unsigned short* __restrict__ wlin, float* __restrict__ biasc) {
  int i = blockIdx.x * 256 + threadIdx.x;
  const int T0 = 3072 * 768;                // Wih both dirs
  const int T1 = 2 * 1536 * 384;            // Whh both dirs
  const int T2 = Cn * 768;                  // Wlin
  const int T3 = 3072;                      // bias
  if (i < T0) {
    int n = i / 768, k = i - n * 768;
    float v = (n < 1536) ? Wih_f[n * 768 + k] : Wih_b[(n - 1536) * 768 + k];
    wih[i] = f2bf(v);
  } else if (i < T0 + T1) {
    int j = i - T0;
    float v = (j < 1536 * 384) ? Whh_f[j] : Whh_b[j - 1536 * 384];
    whh[j] = f2bf(v);
  } else if (i < T0 + T1 + T2) {
    int j = i - T0 - T1;
    wlin[j] = f2bf(Wlin[j]);
  } else if (i < T0 + T1 + T2 + T3) {
    int n = i - T0 - T1 - T2;
    biasc[n] = (n < 1536) ? (bih_f[n] + bhh_f[n]) : (bih_b[n - 1536] + bhh_b[n - 1536]);
  }
}

// ---------------------------------------------------------------------------
// ragged segment mean -> f0p rows [s*64+b][768] (V13: [s][b] order!)
__global__ void pool_kernel(const float* __restrict__ f0, const int* __restrict__ counts,
                            const int* __restrict__ starts, unsigned short* __restrict__ f0p) {
  int idx = blockIdx.x * 256 + threadIdx.x;           // B*S*192 exact
  int dc = idx % 192;
  int rest = idx / 192;
  int s = rest & 511, b = rest >> 9;
  const float4* f4 = (const float4*)f0;
  float4 v;
  if (s < Wn) {
    int st = starts[b * Wn + s], cnt = counts[b * Wn + s];
    v = f4[(size_t)(b * Sn + st) * 192 + dc];
    if (cnt == 2) {
      float4 v2 = f4[(size_t)(b * Sn + st + 1) * 192 + dc];
      v.x = (v.x + v2.x) * 0.5f; v.y = (v.y + v2.y) * 0.5f;
      v.z = (v.z + v2.z) * 0.5f; v.w = (v.w + v2.w) * 0.5f;
    }
  } else {
    v = f4[(size_t)(b * Sn + s) * 192 + dc];
  }
  ushort4 o;
  o.x = f2bf(v.x); o.y = f2bf(v.y); o.z = f2bf(v.z); o.w = f2bf(v.w);
  ((ushort4*)f0p)[(size_t)(s * Bn + b) * 192 + dc] = o;
}

// ---------------------------------------------------------------------------
// FUSED: recur (bid<48) + xp GEMM (bid>=48).
// f0h: f0p rows [s*64+b][768]; recur overwrites row (t*64+b) with h_all --
//      row-aligned with f0p(t), whose readers are exactly the gated tiles.
// xp : [2][512][64][1536] bf16, written via u16 AGENT atomic stores.
// gcnt[32]: group counters (8 mtiles x 24 ntiles = 192 per group).
// htag: [2][2][64][384] u32 = (tag<<16)|bf16 agent mailbox (V8-exact).
__global__ void __launch_bounds__(256, 1)
fused_kernel(const unsigned short* __restrict__ whh,   // [2][1536][384] bf16
             unsigned short* xp,                        // in/out (both roles)
             unsigned short* f0h,                       // f0p in, h_all out (overlay)
             const unsigned short* __restrict__ wih,    // [3072][768] bf16
             const float* __restrict__ biasc,           // [3072]
             unsigned int* htag,
             unsigned int* gcnt) {
  __shared__ __align__(16) char smem[25088];            // union: hlds[2][16*196] | As+Bs
  int bid = blockIdx.x;
  int tid = threadIdx.x, w = tid >> 6, l = tid & 63, lr = l & 15, lq = l >> 4;

  if (bid < NRWG) {
    // ================= recurrence (V8-exact core) =================
    int dir = bid / (NBT * NCK);
    int rem = bid % (NBT * NCK);
    int btile = rem / NCK, chunk = rem % NCK;
    int hwb = chunk * 64 + w * 16;
    int pr = tid >> 4, pk = tid & 15;
    unsigned int (*hlds)[16 * 196] = (unsigned int (*)[16 * 196])smem;

    short8 bfr[4][12];
#pragma unroll
    for (int q = 0; q < 4; ++q)
#pragma unroll
      for (int kf = 0; kf < 12; ++kf)
        bfr[q][kf] = *(const short8*)&whh[((size_t)dir * 1536 + q * 384 + hwb + lr) * 384 + kf * 32 + lq * 8];

    // xp readiness gate: group g = t>>4 ready when gcnt[g]==192
    int lastG = -1;
    auto gate = [&](int tt) {
      int g = tt >> 4;
      if (g != lastG) {
        while (__hip_atomic_load(&gcnt[g], __ATOMIC_RELAXED, __HIP_MEMORY_SCOPE_AGENT) < 192u)
          __builtin_amdgcn_s_sleep(4);
        lastG = g;
        asm volatile("" ::: "memory");      // no xp load hoisting above the gate
      }
    };
    auto ldxp = [&](int tt, unsigned short* dst) {
#pragma unroll
      for (int q = 0; q < 4; ++q)
#pragma unroll
        for (int r = 0; r < 4; ++r) {
          int b = btile * 16 + lq * 4 + r;
          dst[q * 4 + r] = xp[((size_t)((dir * Sn + tt) * Bn + b)) * 1536 + q * 384 + hwb + lr];
        }
    };
    unsigned short xcur[16], xnxt[16];
    int t0 = dir ? (Sn - 1) : 0;
    gate(t0);
    ldxp(t0, xcur);

    f32x4 c0 = (f32x4){0.f, 0.f, 0.f, 0.f};

    for (int it = 0; it < Sn; ++it) {
      int t = dir ? (Sn - 1 - it) : it;
      int tn = (it + 1 < Sn) ? (dir ? (Sn - 2 - it) : (it + 1)) : t;
      gate(tn);
      ldxp(tn, xnxt);                       // issued now, consumed at loop end

      f32x4 acc[4];
#pragma unroll
      for (int q = 0; q < 4; ++q) acc[q] = (f32x4){0.f, 0.f, 0.f, 0.f};

      if (it > 0) {
        const unsigned int expT = (unsigned int)it;
        int slot = (it - 1) & 1;
        const unsigned long long* srow = (const unsigned long long*)
            (htag + (size_t)(dir * 2 + slot) * 64 * 384 + (size_t)(btile * 16 + pr) * 384);
        unsigned long long v[12];
        while (true) {                      // V8 speculative tagged spin
          bool ok = true;
#pragma unroll
          for (int i = 0; i < 12; ++i) {
            unsigned long long x = __hip_atomic_load(&srow[pk + 16 * i],
                                     __ATOMIC_RELAXED, __HIP_MEMORY_SCOPE_AGENT);
            v[i] = x;
            ok &= (((unsigned int)(x >> 16) & 0xffffu) == expT) &
                  ((unsigned int)(x >> 48) == expT);
          }
          if (__all((int)ok)) break;
          __builtin_amdgcn_s_sleep(1);
        }
        unsigned int* dst = hlds[it & 1];
#pragma unroll
        for (int i = 0; i < 12; ++i)
          dst[pr * 196 + pk + 16 * i] = ((unsigned int)v[i] & 0xffffu) |
                                        (((unsigned int)(v[i] >> 32) & 0xffffu) << 16);
        __syncthreads();                    // the ONLY barrier per step
        const char* src = (const char*)hlds[it & 1];
#pragma unroll
        for (int kf = 0; kf < 12; ++kf) {
          short8 a = *(const short8*)(src + lr * 784 + kf * 64 + lq * 16);
#pragma unroll
          for (int q = 0; q < 4; ++q)
            acc[q] = __builtin_amdgcn_mfma_f32_16x16x32_bf16(a, bfr[q][kf], acc[q], 0, 0, 0);
        }
      }

      // cell (xp folded here) + publish (producer NEVER waits)
      unsigned int outTag = (unsigned int)(it + 1) << 16;
      int oslot = it & 1;
      unsigned int* obase = htag + (size_t)(dir * 2 + oslot) * 64 * 384;
      unsigned short hb16v[4];
#pragma unroll
      for (int r = 0; r < 4; ++r) {
        float iv = sigm(acc[0][r] + bf2f(xcur[0 * 4 + r]));
        float fv = sigm(acc[1][r] + bf2f(xcur[1 * 4 + r]));
        float gv = tanhft(acc[2][r] + bf2f(xcur[2 * 4 + r]));
        float ov = sigm(acc[3][r] + bf2f(xcur[3 * 4 + r]));
        float cf = fv * c0[r] + iv * gv;
        c0[r] = cf;
        float hv = ov * tanhft(cf);
        hb16v[r] = f2bf(hv);
        int b = btile * 16 + lq * 4 + r;
        __hip_atomic_store(&obase[(size_t)b * 384 + hwb + lr],
                           outTag | hb16v[r], __ATOMIC_RELAXED, __HIP_MEMORY_SCOPE_AGENT);
      }
#pragma unroll
      for (int r = 0; r < 4; ++r) {         // h_all row (t*64+b): clobbers only f0p(t)
        int b = btile * 16 + lq * 4 + r;
        f0h[((size_t)(t * Bn + b)) * 768 + dir * Hn + hwb + lr] = hb16v[r];
      }
#pragma unroll
      for (int i = 0; i < 16; ++i) xcur[i] = xnxt[i];
    }
    return;
  }

  // ================= xp GEMM tile =================
  // priority map: early blocks produce mtiles from both t-ends.
  int gb = bid - NRWG;                      // 0..6143
  int q = gb / 48, r = gb % 48;
  int mtile = (r < 24) ? q : (255 - q);     // 256 mtiles (2 t x 64 b each)
  int ntile = r % 24;                       // 24 ntiles
  unsigned short* As = (unsigned short*)smem;
  unsigned short* Bs = (unsigned short*)(smem + 8192);
  int mBase = mtile * 128, nBase = ntile * 128;
  int mw = (w & 1) * 64, nw = (w >> 1) * 64;
  f32x4 acc[4][4];
#pragma unroll
  for (int mt = 0; mt < 4; ++mt)
#pragma unroll
    for (int nt = 0; nt < 4; ++nt) acc[mt][nt] = (f32x4){0.f, 0.f, 0.f, 0.f};

  for (int kb = 0; kb < 24; ++kb) {
    int k0 = kb * 32;
#pragma unroll
    for (int j = 0; j < 2; ++j) {
      int g = j * 256 + tid;
      int row = g >> 2, kc = (g & 3) * 8;
      GLL16(f0h + (size_t)(mBase + row) * 768 + k0 + kc, (char*)As + (j * 256 + w * 64) * 16);
      GLL16(wih + (size_t)(nBase + row) * 768 + k0 + kc, (char*)Bs + (j * 256 + w * 64) * 16);
    }
    __syncthreads();
    short8 af[4], bfv[4];
#pragma unroll
    for (int mt = 0; mt < 4; ++mt) af[mt] = *(const short8*)&As[(mw + mt * 16 + lr) * 32 + lq * 8];
#pragma unroll
    for (int nt = 0; nt < 4; ++nt) bfv[nt] = *(const short8*)&Bs[(nw + nt * 16 + lr) * 32 + lq * 8];
#pragma unroll
    for (int mt = 0; mt < 4; ++mt)
#pragma unroll
      for (int nt = 0; nt < 4; ++nt)
        acc[mt][nt] = __builtin_amdgcn_mfma_f32_16x16x32_bf16(af[mt], bfv[nt], acc[mt][nt], 0, 0, 0);
    __syncthreads();
  }
  // epilogue: +bias, u16 AGENT atomic stores (write-through -> IC-visible)
#pragma unroll
  for (int mt = 0; mt < 4; ++mt) {
#pragma unroll
    for (int rr = 0; rr < 4; ++rr) {
      int m = mBase + mw + mt * 16 + lq * 4 + rr;
      int t = m >> 6, b = m & 63;           // rows are [s*64+b]
#pragma unroll
      for (int nt = 0; nt < 4; ++nt) {
        int n = nBase + nw + nt * 16 + lr;
        int d = (n >= 1536) ? 1 : 0;
        int gI = n - d * 1536;
        unsigned short val = f2bf(acc[mt][nt][rr] + biasc[n]);
        __hip_atomic_store(&xp[((size_t)((d * Sn + t) * Bn + b)) * 1536 + gI], val,
                           __ATOMIC_RELAXED, __HIP_MEMORY_SCOPE_AGENT);
      }
    }
  }
  asm volatile("s_waitcnt vmcnt(0)" ::: "memory");      // all stores at IC
  __syncthreads();                                       // whole wg drained
  if (tid == 0)
    __hip_atomic_fetch_add(&gcnt[mtile >> 3], 1u, __ATOMIC_RELAXED,
                           __HIP_MEMORY_SCOPE_AGENT);
}

// ---------------------------------------------------------------------------
// out GEMM: A = h_all rows [t*64+b][768] bf16, B = wlin [425][768] bf16
// out[(b*S+t)*C + n] fp32 = A@B^T + blin
__global__ void gemm_out(const unsigned short* __restrict__ A, const unsigned short* __restrict__ Bw,
                         const float* __restrict__ blin, float* __restrict__ out) {
  __shared__ __align__(16) unsigned short As[128 * 32];
  __shared__ __align__(16) unsigned short Bs[128 * 32];
  int tid = threadIdx.x, w = tid >> 6, l = tid & 63, lr = l & 15, lq = l >> 4;
  int mBase = blockIdx.x * 128, nBase = blockIdx.y * 128;
  int mw = (w & 1) * 64, nw = (w >> 1) * 64;
  f32x4 acc[4][4];
#pragma unroll
  for (int mt = 0; mt < 4; ++mt)
#pragma unroll
    for (int nt = 0; nt < 4; ++nt) acc[mt][nt] = (f32x4){0.f, 0.f, 0.f, 0.f};

  for (int kb = 0; kb < 24; ++kb) {
    int k0 = kb * 32;
#pragma unroll
    for (int j = 0; j < 2; ++j) {
      int g = j * 256 + tid;
      int row = g >> 2, kc = (g & 3) * 8;
      int nr = nBase + row; if (nr > Cn - 1) nr = Cn - 1;   // clamp: Wlin has 425 rows
      GLL16(A + (size_t)(mBase + row) * 768 + k0 + kc, (char*)As + (j * 256 + w * 64) * 16);
      GLL16(Bw + (size_t)nr * 768 + k0 + kc, (char*)Bs + (j * 256 + w * 64) * 16);
    }
    __syncthreads();
    short8 af[4], bfv[4];
#pragma unroll
    for (int mt = 0; mt < 4; ++mt) af[mt] = *(const short8*)&As[(mw + mt * 16 + lr) * 32 + lq * 8];
#pragma unroll
    for (int nt = 0; nt < 4; ++nt) bfv[nt] = *(const short8*)&Bs[(nw + nt * 16 + lr) * 32 + lq * 8];
#pragma unroll
    for (int mt = 0; mt < 4; ++mt)
#pragma unroll
      for (int nt = 0; nt < 4; ++nt)
        acc[mt][nt] = __builtin_amdgcn_mfma_f32_16x16x32_bf16(af[mt], bfv[nt], acc[mt][nt], 0, 0, 0);
    __syncthreads();
  }
#pragma unroll
  for (int nt = 0; nt < 4; ++nt) {
    int n = nBase + nw + nt * 16 + lr;
    if (n < Cn) {
      float bias = blin[n];
#pragma unroll
      for (int mt = 0; mt < 4; ++mt) {
#pragma unroll
        for (int r = 0; r < 4; ++r) {
          int m = mBase + mw + mt * 16 + lq * 4 + r;
          int t = m >> 6, b = m & 63;       // rows are [t*64+b]
          out[((size_t)(b * Sn + t)) * Cn + n] = acc[mt][nt][r] + bias;
        }
      }
    }
  }
}

// ---------------------------------------------------------------------------
extern "C" void kernel_launch(void* const* d_in, const int* in_sizes, int n_in,
                              void* d_out, int out_size, void* d_ws, size_t ws_size,
                              hipStream_t stream) {
  (void)in_sizes; (void)n_in; (void)out_size;
  const float* f0     = (const float*)d_in[0];
  const int*   counts = (const int*)  d_in[1];
  const float* Wih_f  = (const float*)d_in[2];
  const float* Whh_f  = (const float*)d_in[3];
  const float* bih_f  = (const float*)d_in[4];
  const float* bhh_f  = (const float*)d_in[5];
  const float* Wih_b  = (const float*)d_in[6];
  const float* Whh_b  = (const float*)d_in[7];
  const float* bih_b  = (const float*)d_in[8];
  const float* bhh_b  = (const float*)d_in[9];
  const float* Wlin   = (const float*)d_in[10];
  const float* blin   = (const float*)d_in[11];
  float* out = (float*)d_out;

  char* ws = (char*)d_ws;
  size_t o = 0;
  auto alloc = [&](size_t bytes) { size_t cur = o; o += (bytes + 255) & ~(size_t)255; return cur; };
  size_t o_f0p    = alloc((size_t)Bn * Sn * Dn * 2);        // 50.3 MB (f0p; overlaid h_all)
  size_t o_xp     = alloc((size_t)2 * Sn * Bn * G4H * 2);   // 201.3 MB
  size_t o_wih    = alloc((size_t)3072 * 768 * 2);
  size_t o_whh    = alloc((size_t)2 * 1536 * 384 * 2);
  size_t o_wlin   = alloc((size_t)Cn * 768 * 2);
  size_t o_bias   = alloc((size_t)3072 * 4);
  size_t o_starts = alloc((size_t)Bn * Wn * 4);
  size_t o_htag   = alloc((size_t)2 * 2 * 64 * 384 * 4);    // 384 KB, [dir][slot][b][h]
  size_t o_gcnt   = alloc((size_t)32 * 4);                  // contiguous after htag
  if (o > ws_size) return;  // ~261 MiB of workspace

  unsigned short* f0h   = (unsigned short*)(ws + o_f0p);
  unsigned short* xp    = (unsigned short*)(ws + o_xp);
  unsigned short* wih   = (unsigned short*)(ws + o_wih);
  unsigned short* whh   = (unsigned short*)(ws + o_whh);
  unsigned short* wlin  = (unsigned short*)(ws + o_wlin);
  float*          biasc = (float*)(ws + o_bias);
  int*            starts= (int*)(ws + o_starts);
  unsigned int*   htag  = (unsigned int*)(ws + o_htag);
  unsigned int*   gcnt  = (unsigned int*)(ws + o_gcnt);

  {
    int nwords = 2 * 2 * 64 * 384 + 32;                     // htag + gcnt (contiguous)
    zero_comm<<<(nwords + 255) / 256, 256, 0, stream>>>(htag, nwords);
  }
  scan_starts<<<Bn, 256, 0, stream>>>(counts, starts);
  {
    int total = 3072 * 768 + 2 * 1536 * 384 + Cn * 768 + 3072;
    prep_cast<<<(total + 255) / 256, 256, 0, stream>>>(Wih_f, Wih_b, Whh_f, Whh_b, Wlin,
                                                       bih_f, bhh_f, bih_b, bhh_b,
                                                       wih, whh, wlin, biasc);
  }
  pool_kernel<<<(Bn * Sn * 192) / 256, 256, 0, stream>>>(f0, counts, starts, f0h);
  fused_kernel<<<NRWG + 6144, 256, 0, stream>>>(whh, xp, f0h, wih, biasc, htag, gcnt);
  gemm_out<<<dim3(256, 4), 256, 0, stream>>>(f0h, wlin, blin, out);
}

// Round 8
// 1892.816 us; speedup vs baseline: 3.6688x; 1.0050x over previous
//
#include <hip/hip_runtime.h>
#include <stdint.h>

// ---------------------------------------------------------------------------
// LSTMSupertaggingModel: segment-mean-pool -> BiLSTM(H=384) -> Linear(C=425)
// B=64, S=512, D=768, W=256, H=384, C=425
//
// V14 = V13 with ONE variable changed: LDS footprint padded to 84 KB so
// every block owns a CU exclusively (84KB > 160KB/2 -> 1 wg/CU).
//  - V13 post-mortem: fusion absorbed gemm_xp (~300us) but recur slowed
//    1405 -> ~1693us. Suspect: gemm wgs co-resident on recur CUs (25KB LDS
//    allowed 6 wgs/CU) queue the spin's IC loads behind bulk global_load_lds
//    staging on the shared TA/L1 path + steal issue slots. Exclusive CUs
//    isolate that from fabric congestion (the other candidate).
//  - gemm throughput at 1 wg/CU: 6144 tiles / 208 CUs ~= 30 serial tiles
//    x ~13us = ~390us << 1405us recur -> still fully hidden.
//  - dispatch order: recur blocks 0..47 first -> each lands on a distinct
//    CU (1 wg/CU) before any gemm block; no deadlock mode exists.
//  - V13 structure kept: rows [s*64+b] (tile<->consumption alignment, row-
//    aligned f0p/h_all overlay), u16 AGENT xp stores + vmcnt + per-wg
//    atomicAdd on gcnt[32] (192 tiles/group), both-ends priority order,
//    V8-exact mailbox/spin core, ldxp prefetch folded after MFMA.
//  - exchange-latency line CLOSED (V9-V12): agent mailbox ~6600cy/step is
//    robust; the remaining game is keeping its environment quiet.
// ---------------------------------------------------------------------------

typedef __attribute__((ext_vector_type(8))) short short8;
typedef __attribute__((ext_vector_type(4))) float f32x4;

static constexpr int Bn = 64, Sn = 512, Dn = 768, Wn = 256, Hn = 384, Cn = 425;
static constexpr int G4H = 4 * Hn;          // 1536
static constexpr int NBT = 4;               // batch tiles of 16
static constexpr int NCK = 6;               // h-chunks of 64 rows per dir
static constexpr int NRWG = 2 * NBT * NCK;  // 48 recur wgs

__device__ __forceinline__ unsigned short f2bf(float f) {
  unsigned int u = __float_as_uint(f);
  u += 0x7FFFu + ((u >> 16) & 1u);          // round-to-nearest-even
  return (unsigned short)(u >> 16);
}
__device__ __forceinline__ float bf2f(unsigned short h) {
  return __uint_as_float(((unsigned int)h) << 16);
}
__device__ __forceinline__ float sigm(float x)  { return 1.f / (1.f + __expf(-x)); }
__device__ __forceinline__ float tanhft(float x){ return 1.f - 2.f / (__expf(2.f * x) + 1.f); }

// async global->LDS, 16B per lane; LDS dest = wave-uniform base + lane*16
#define GLL16(gp, lp) __builtin_amdgcn_global_load_lds( \
  (const __attribute__((address_space(1))) unsigned int*)(gp), \
  (__attribute__((address_space(3))) unsigned int*)(lp), 16, 0, 0)

// ---------------------------------------------------------------------------
// zero comm region through the UC/atomic path (visible to agent-scope loads)
__global__ void zero_comm(unsigned int* p, int nwords) {
  int i = blockIdx.x * 256 + threadIdx.x;
  if (i < nwords)
    __hip_atomic_store(&p[i], 0u, __ATOMIC_RELAXED, __HIP_MEMORY_SCOPE_AGENT);
}

// ---------------------------------------------------------------------------
__global__ void scan_starts(const int* __restrict__ counts, int* __restrict__ starts) {
  int b = blockIdx.x, j = threadIdx.x;      // 64 blocks x 256 threads
  __shared__ int sm[256];
  int c = counts[b * Wn + j];
  sm[j] = c;
  __syncthreads();
  for (int off = 1; off < 256; off <<= 1) {
    int v = (j >= off) ? sm[j - off] : 0;
    __syncthreads();
    sm[j] += v;
    __syncthreads();
  }
  starts[b * Wn + j] = sm[j] - c;           // exclusive
}

// ---------------------------------------------------------------------------
__global__ void prep_cast(const float* __restrict__ Wih_f, const float* __restrict__ Wih_b,
                          const float* __restrict__ Whh_f, const float* __restrict__ Whh_b,
                          const float* __restrict__ Wlin,
                          const float* __restrict__ bih_f, const float* __restrict__ bhh_f,
                          const float* __restrict__ bih_b, const float* __restrict__ bhh_b,
                          unsigned short* __restrict__ wih, unsigned short* __restrict__ whh,
                          unsigned short* __restrict__ wlin, float* __restrict__ biasc) {
  int i = blockIdx.x * 256 + threadIdx.x;
  const int T0 = 3072 * 768;                // Wih both dirs
  const int T1 = 2 * 1536 * 384;            // Whh both dirs
  const int T2 = Cn * 768;                  // Wlin
  const int T3 = 3072;                      // bias
  if (i < T0) {
    int n = i / 768, k = i - n * 768;
    float v = (n < 1536) ? Wih_f[n * 768 + k] : Wih_b[(n - 1536) * 768 + k];
    wih[i] = f2bf(v);
  } else if (i < T0 + T1) {
    int j = i - T0;
    float v = (j < 1536 * 384) ? Whh_f[j] : Whh_b[j - 1536 * 384];
    whh[j] = f2bf(v);
  } else if (i < T0 + T1 + T2) {
    int j = i - T0 - T1;
    wlin[j] = f2bf(Wlin[j]);
  } else if (i < T0 + T1 + T2 + T3) {
    int n = i - T0 - T1 - T2;
    biasc[n] = (n < 1536) ? (bih_f[n] + bhh_f[n]) : (bih_b[n - 1536] + bhh_b[n - 1536]);
  }
}

// ---------------------------------------------------------------------------
// ragged segment mean -> f0p rows [s*64+b][768]
__global__ void pool_kernel(const float* __restrict__ f0, const int* __restrict__ counts,
                            const int* __restrict__ starts, unsigned short* __restrict__ f0p) {
  int idx = blockIdx.x * 256 + threadIdx.x;           // B*S*192 exact
  int dc = idx % 192;
  int rest = idx / 192;
  int s = rest & 511, b = rest >> 9;
  const float4* f4 = (const float4*)f0;
  float4 v;
  if (s < Wn) {
    int st = starts[b * Wn + s], cnt = counts[b * Wn + s];
    v = f4[(size_t)(b * Sn + st) * 192 + dc];
    if (cnt == 2) {
      float4 v2 = f4[(size_t)(b * Sn + st + 1) * 192 + dc];
      v.x = (v.x + v2.x) * 0.5f; v.y = (v.y + v2.y) * 0.5f;
      v.z = (v.z + v2.z) * 0.5f; v.w = (v.w + v2.w) * 0.5f;
    }
  } else {
    v = f4[(size_t)(b * Sn + s) * 192 + dc];
  }
  ushort4 o;
  o.x = f2bf(v.x); o.y = f2bf(v.y); o.z = f2bf(v.z); o.w = f2bf(v.w);
  ((ushort4*)f0p)[(size_t)(s * Bn + b) * 192 + dc] = o;
}

// ---------------------------------------------------------------------------
// FUSED: recur (bid<48) + xp GEMM (bid>=48). 84KB LDS -> 1 wg/CU (V14).
// f0h: f0p rows [s*64+b][768]; recur overwrites row (t*64+b) with h_all.
// xp : [2][512][64][1536] bf16, written via u16 AGENT atomic stores.
// gcnt[32]: group counters (8 mtiles x 24 ntiles = 192 per group).
// htag: [2][2][64][384] u32 = (tag<<16)|bf16 agent mailbox (V8-exact).
__global__ void __launch_bounds__(256, 1)
fused_kernel(const unsigned short* __restrict__ whh,   // [2][1536][384] bf16
             unsigned short* xp,                        // in/out (both roles)
             unsigned short* f0h,                       // f0p in, h_all out (overlay)
             const unsigned short* __restrict__ wih,    // [3072][768] bf16
             const float* __restrict__ biasc,           // [3072]
             unsigned int* htag,
             unsigned int* gcnt) {
  // 84KB static LDS: only 25088 B used, padded so 84KB > 160KB/2 -> exactly
  // one wg per CU (recur CUs private; spin never queues behind gemm staging).
  __shared__ __align__(16) char smem[86016];
  int bid = blockIdx.x;
  int tid = threadIdx.x, w = tid >> 6, l = tid & 63, lr = l & 15, lq = l >> 4;

  if (bid < NRWG) {
    // ================= recurrence (V8-exact core) =================
    int dir = bid / (NBT * NCK);
    int rem = bid % (NBT * NCK);
    int btile = rem / NCK, chunk = rem % NCK;
    int hwb = chunk * 64 + w * 16;
    int pr = tid >> 4, pk = tid & 15;
    unsigned int (*hlds)[16 * 196] = (unsigned int (*)[16 * 196])smem;

    short8 bfr[4][12];
#pragma unroll
    for (int q = 0; q < 4; ++q)
#pragma unroll
      for (int kf = 0; kf < 12; ++kf)
        bfr[q][kf] = *(const short8*)&whh[((size_t)dir * 1536 + q * 384 + hwb + lr) * 384 + kf * 32 + lq * 8];

    // xp readiness gate: group g = t>>4 ready when gcnt[g]==192
    int lastG = -1;
    auto gate = [&](int tt) {
      int g = tt >> 4;
      if (g != lastG) {
        while (__hip_atomic_load(&gcnt[g], __ATOMIC_RELAXED, __HIP_MEMORY_SCOPE_AGENT) < 192u)
          __builtin_amdgcn_s_sleep(4);
        lastG = g;
        asm volatile("" ::: "memory");      // no xp load hoisting above the gate
      }
    };
    auto ldxp = [&](int tt, unsigned short* dst) {
#pragma unroll
      for (int q = 0; q < 4; ++q)
#pragma unroll
        for (int r = 0; r < 4; ++r) {
          int b = btile * 16 + lq * 4 + r;
          dst[q * 4 + r] = xp[((size_t)((dir * Sn + tt) * Bn + b)) * 1536 + q * 384 + hwb + lr];
        }
    };
    unsigned short xcur[16], xnxt[16];
    int t0 = dir ? (Sn - 1) : 0;
    gate(t0);
    ldxp(t0, xcur);

    f32x4 c0 = (f32x4){0.f, 0.f, 0.f, 0.f};

    for (int it = 0; it < Sn; ++it) {
      int t = dir ? (Sn - 1 - it) : it;
      int tn = (it + 1 < Sn) ? (dir ? (Sn - 2 - it) : (it + 1)) : t;
      gate(tn);
      ldxp(tn, xnxt);                       // issued now, consumed at loop end

      f32x4 acc[4];
#pragma unroll
      for (int q = 0; q < 4; ++q) acc[q] = (f32x4){0.f, 0.f, 0.f, 0.f};

      if (it > 0) {
        const unsigned int expT = (unsigned int)it;
        int slot = (it - 1) & 1;
        const unsigned long long* srow = (const unsigned long long*)
            (htag + (size_t)(dir * 2 + slot) * 64 * 384 + (size_t)(btile * 16 + pr) * 384);
        unsigned long long v[12];
        while (true) {                      // V8 speculative tagged spin
          bool ok = true;
#pragma unroll
          for (int i = 0; i < 12; ++i) {
            unsigned long long x = __hip_atomic_load(&srow[pk + 16 * i],
                                     __ATOMIC_RELAXED, __HIP_MEMORY_SCOPE_AGENT);
            v[i] = x;
            ok &= (((unsigned int)(x >> 16) & 0xffffu) == expT) &
                  ((unsigned int)(x >> 48) == expT);
          }
          if (__all((int)ok)) break;
          __builtin_amdgcn_s_sleep(1);
        }
        unsigned int* dst = hlds[it & 1];
#pragma unroll
        for (int i = 0; i < 12; ++i)
          dst[pr * 196 + pk + 16 * i] = ((unsigned int)v[i] & 0xffffu) |
                                        (((unsigned int)(v[i] >> 32) & 0xffffu) << 16);
        __syncthreads();                    // the ONLY barrier per step
        const char* src = (const char*)hlds[it & 1];
#pragma unroll
        for (int kf = 0; kf < 12; ++kf) {
          short8 a = *(const short8*)(src + lr * 784 + kf * 64 + lq * 16);
#pragma unroll
          for (int q = 0; q < 4; ++q)
            acc[q] = __builtin_amdgcn_mfma_f32_16x16x32_bf16(a, bfr[q][kf], acc[q], 0, 0, 0);
        }
      }

      // cell (xp folded here) + publish (producer NEVER waits)
      unsigned int outTag = (unsigned int)(it + 1) << 16;
      int oslot = it & 1;
      unsigned int* obase = htag + (size_t)(dir * 2 + oslot) * 64 * 384;
      unsigned short hb16v[4];
#pragma unroll
      for (int r = 0; r < 4; ++r) {
        float iv = sigm(acc[0][r] + bf2f(xcur[0 * 4 + r]));
        float fv = sigm(acc[1][r] + bf2f(xcur[1 * 4 + r]));
        float gv = tanhft(acc[2][r] + bf2f(xcur[2 * 4 + r]));
        float ov = sigm(acc[3][r] + bf2f(xcur[3 * 4 + r]));
        float cf = fv * c0[r] + iv * gv;
        c0[r] = cf;
        float hv = ov * tanhft(cf);
        hb16v[r] = f2bf(hv);
        int b = btile * 16 + lq * 4 + r;
        __hip_atomic_store(&obase[(size_t)b * 384 + hwb + lr],
                           outTag | hb16v[r], __ATOMIC_RELAXED, __HIP_MEMORY_SCOPE_AGENT);
      }
#pragma unroll
      for (int r = 0; r < 4; ++r) {         // h_all row (t*64+b): clobbers only f0p(t)
        int b = btile * 16 + lq * 4 + r;
        f0h[((size_t)(t * Bn + b)) * 768 + dir * Hn + hwb + lr] = hb16v[r];
      }
#pragma unroll
      for (int i = 0; i < 16; ++i) xcur[i] = xnxt[i];
    }
    return;
  }

  // ================= xp GEMM tile =================
  // priority map: early blocks produce mtiles from both t-ends.
  int gb = bid - NRWG;                      // 0..6143
  int q = gb / 48, r = gb % 48;
  int mtile = (r < 24) ? q : (255 - q);     // 256 mtiles (2 t x 64 b each)
  int ntile = r % 24;                       // 24 ntiles
  unsigned short* As = (unsigned short*)smem;
  unsigned short* Bs = (unsigned short*)(smem + 8192);
  int mBase = mtile * 128, nBase = ntile * 128;
  int mw = (w & 1) * 64, nw = (w >> 1) * 64;
  f32x4 acc[4][4];
#pragma unroll
  for (int mt = 0; mt < 4; ++mt)
#pragma unroll
    for (int nt = 0; nt < 4; ++nt) acc[mt][nt] = (f32x4){0.f, 0.f, 0.f, 0.f};

  for (int kb = 0; kb < 24; ++kb) {
    int k0 = kb * 32;
#pragma unroll
    for (int j = 0; j < 2; ++j) {
      int g = j * 256 + tid;
      int row = g >> 2, kc = (g & 3) * 8;
      GLL16(f0h + (size_t)(mBase + row) * 768 + k0 + kc, (char*)As + (j * 256 + w * 64) * 16);
      GLL16(wih + (size_t)(nBase + row) * 768 + k0 + kc, (char*)Bs + (j * 256 + w * 64) * 16);
    }
    __syncthreads();
    short8 af[4], bfv[4];
#pragma unroll
    for (int mt = 0; mt < 4; ++mt) af[mt] = *(const short8*)&As[(mw + mt * 16 + lr) * 32 + lq * 8];
#pragma unroll
    for (int nt = 0; nt < 4; ++nt) bfv[nt] = *(const short8*)&Bs[(nw + nt * 16 + lr) * 32 + lq * 8];
#pragma unroll
    for (int mt = 0; mt < 4; ++mt)
#pragma unroll
      for (int nt = 0; nt < 4; ++nt)
        acc[mt][nt] = __builtin_amdgcn_mfma_f32_16x16x32_bf16(af[mt], bfv[nt], acc[mt][nt], 0, 0, 0);
    __syncthreads();
  }
  // epilogue: +bias, u16 AGENT atomic stores (write-through -> IC-visible)
#pragma unroll
  for (int mt = 0; mt < 4; ++mt) {
#pragma unroll
    for (int rr = 0; rr < 4; ++rr) {
      int m = mBase + mw + mt * 16 + lq * 4 + rr;
      int t = m >> 6, b = m & 63;           // rows are [s*64+b]
#pragma unroll
      for (int nt = 0; nt < 4; ++nt) {
        int n = nBase + nw + nt * 16 + lr;
        int d = (n >= 1536) ? 1 : 0;
        int gI = n - d * 1536;
        unsigned short val = f2bf(acc[mt][nt][rr] + biasc[n]);
        __hip_atomic_store(&xp[((size_t)((d * Sn + t) * Bn + b)) * 1536 + gI], val,
                           __ATOMIC_RELAXED, __HIP_MEMORY_SCOPE_AGENT);
      }
    }
  }
  asm volatile("s_waitcnt vmcnt(0)" ::: "memory");      // all stores at IC
  __syncthreads();                                       // whole wg drained
  if (tid == 0)
    __hip_atomic_fetch_add(&gcnt[mtile >> 3], 1u, __ATOMIC_RELAXED,
                           __HIP_MEMORY_SCOPE_AGENT);
}

// ---------------------------------------------------------------------------
// out GEMM: A = h_all rows [t*64+b][768] bf16, B = wlin [425][768] bf16
// out[(b*S+t)*C + n] fp32 = A@B^T + blin
__global__ void gemm_out(const unsigned short* __restrict__ A, const unsigned short* __restrict__ Bw,
                         const float* __restrict__ blin, float* __restrict__ out) {
  __shared__ __align__(16) unsigned short As[128 * 32];
  __shared__ __align__(16) unsigned short Bs[128 * 32];
  int tid = threadIdx.x, w = tid >> 6, l = tid & 63, lr = l & 15, lq = l >> 4;
  int mBase = blockIdx.x * 128, nBase = blockIdx.y * 128;
  int mw = (w & 1) * 64, nw = (w >> 1) * 64;
  f32x4 acc[4][4];
#pragma unroll
  for (int mt = 0; mt < 4; ++mt)
#pragma unroll
    for (int nt = 0; nt < 4; ++nt) acc[mt][nt] = (f32x4){0.f, 0.f, 0.f, 0.f};

  for (int kb = 0; kb < 24; ++kb) {
    int k0 = kb * 32;
#pragma unroll
    for (int j = 0; j < 2; ++j) {
      int g = j * 256 + tid;
      int row = g >> 2, kc = (g & 3) * 8;
      int nr = nBase + row; if (nr > Cn - 1) nr = Cn - 1;   // clamp: Wlin has 425 rows
      GLL16(A + (size_t)(mBase + row) * 768 + k0 + kc, (char*)As + (j * 256 + w * 64) * 16);
      GLL16(Bw + (size_t)nr * 768 + k0 + kc, (char*)Bs + (j * 256 + w * 64) * 16);
    }
    __syncthreads();
    short8 af[4], bfv[4];
#pragma unroll
    for (int mt = 0; mt < 4; ++mt) af[mt] = *(const short8*)&As[(mw + mt * 16 + lr) * 32 + lq * 8];
#pragma unroll
    for (int nt = 0; nt < 4; ++nt) bfv[nt] = *(const short8*)&Bs[(nw + nt * 16 + lr) * 32 + lq * 8];
#pragma unroll
    for (int mt = 0; mt < 4; ++mt)
#pragma unroll
      for (int nt = 0; nt < 4; ++nt)
        acc[mt][nt] = __builtin_amdgcn_mfma_f32_16x16x32_bf16(af[mt], bfv[nt], acc[mt][nt], 0, 0, 0);
    __syncthreads();
  }
#pragma unroll
  for (int nt = 0; nt < 4; ++nt) {
    int n = nBase + nw + nt * 16 + lr;
    if (n < Cn) {
      float bias = blin[n];
#pragma unroll
      for (int mt = 0; mt < 4; ++mt) {
#pragma unroll
        for (int r = 0; r < 4; ++r) {
          int m = mBase + mw + mt * 16 + lq * 4 + r;
          int t = m >> 6, b = m & 63;       // rows are [t*64+b]
          out[((size_t)(b * Sn + t)) * Cn + n] = acc[mt][nt][r] + bias;
        }
      }
    }
  }
}

// ---------------------------------------------------------------------------
extern "C" void kernel_launch(void* const* d_in, const int* in_sizes, int n_in,
                              void* d_out, int out_size, void* d_ws, size_t ws_size,
                              hipStream_t stream) {
  (void)in_sizes; (void)n_in; (void)out_size;
  const float* f0     = (const float*)d_in[0];
  const int*   counts = (const int*)  d_in[1];
  const float* Wih_f  = (const float*)d_in[2];
  const float* Whh_f  = (const float*)d_in[3];
  const float* bih_f  = (const float*)d_in[4];
  const float* bhh_f  = (const float*)d_in[5];
  const float* Wih_b  = (const float*)d_in[6];
  const float* Whh_b  = (const float*)d_in[7];
  const float* bih_b  = (const float*)d_in[8];
  const float* bhh_b  = (const float*)d_in[9];
  const float* Wlin   = (const float*)d_in[10];
  const float* blin   = (const float*)d_in[11];
  float* out = (float*)d_out;

  char* ws = (char*)d_ws;
  size_t o = 0;
  auto alloc = [&](size_t bytes) { size_t cur = o; o += (bytes + 255) & ~(size_t)255; return cur; };
  size_t o_f0p    = alloc((size_t)Bn * Sn * Dn * 2);        // 50.3 MB (f0p; overlaid h_all)
  size_t o_xp     = alloc((size_t)2 * Sn * Bn * G4H * 2);   // 201.3 MB
  size_t o_wih    = alloc((size_t)3072 * 768 * 2);
  size_t o_whh    = alloc((size_t)2 * 1536 * 384 * 2);
  size_t o_wlin   = alloc((size_t)Cn * 768 * 2);
  size_t o_bias   = alloc((size_t)3072 * 4);
  size_t o_starts = alloc((size_t)Bn * Wn * 4);
  size_t o_htag   = alloc((size_t)2 * 2 * 64 * 384 * 4);    // 384 KB, [dir][slot][b][h]
  size_t o_gcnt   = alloc((size_t)32 * 4);                  // contiguous after htag
  if (o > ws_size) return;  // ~261 MiB of workspace

  unsigned short* f0h   = (unsigned short*)(ws + o_f0p);
  unsigned short* xp    = (unsigned short*)(ws + o_xp);
  unsigned short* wih   = (unsigned short*)(ws + o_wih);
  unsigned short* whh   = (unsigned short*)(ws + o_whh);
  unsigned short* wlin  = (unsigned short*)(ws + o_wlin);
  float*          biasc = (float*)(ws + o_bias);
  int*            starts= (int*)(ws + o_starts);
  unsigned int*   htag  = (unsigned int*)(ws + o_htag);
  unsigned int*   gcnt  = (unsigned int*)(ws + o_gcnt);

  {
    int nwords = 2 * 2 * 64 * 384 + 32;                     // htag + gcnt (contiguous)
    zero_comm<<<(nwords + 255) / 256, 256, 0, stream>>>(htag, nwords);
  }
  scan_starts<<<Bn, 256, 0, stream>>>(counts, starts);
  {
    int total = 3072 * 768 + 2 * 1536 * 384 + Cn * 768 + 3072;
    prep_cast<<<(total + 255) / 256, 256, 0, stream>>>(Wih_f, Wih_b, Whh_f, Whh_b, Wlin,
                                                       bih_f, bhh_f, bih_b, bhh_b,
                                                       wih, whh, wlin, biasc);
  }
  pool_kernel<<<(Bn * Sn * 192) / 256, 256, 0, stream>>>(f0, counts, starts, f0h);
  fused_kernel<<<NRWG + 6144, 256, 0, stream>>>(whh, xp, f0h, wih, biasc, htag, gcnt);
  gemm_out<<<dim3(256, 4), 256, 0, stream>>>(f0h, wlin, blin, out);
}

// Round 9
// 1629.922 us; speedup vs baseline: 4.2605x; 1.1613x over previous
//
#include <hip/hip_runtime.h>
#include <stdint.h>

// ---------------------------------------------------------------------------
// LSTMSupertaggingModel: segment-mean-pool -> BiLSTM(H=384) -> Linear(C=425)
// B=64, S=512, D=768, W=256, H=384, C=425
//
// V15 = V14 with ONE variable changed: the xp GEMM epilogue no longer issues
// 64 sub-sector u16 agent-atomic stores per thread (~100M IC atomic RMW ops
// -> +200MB FETCH, and the diagnosed source of the recur spin's k~3.7x
// slowdown during the gemm phase: mailbox ops queue behind the RMW flood in
// the IC atomic pipeline). Instead:
//  - stage the 128x128 bf16 tile (+bias) in LDS (row stride 132 u16 to
//    de-conflict the u64 re-read),
//  - store with u64 agent atomics where EACH instruction's 8-lane groups
//    write full 64B sectors (lane l: row group l>>3, sector fill (l&7)*8B;
//    16 iters = 4 row-octets x 4 sectors) -> 16 ops/thread, zero RMW.
//  - V14 post-mortem: 84KB LDS (1 wg/CU) changed NOTHING vs V13 -> CU-level
//    co-residency falsified; interference is fabric-level. Keep the padding
//    (harmless, keeps CUs private).
//  - V13 structure kept: rows [s*64+b], gcnt gating (32 groups x 192 tiles),
//    both-ends priority order, V8-exact mailbox/spin recur core, ldxp
//    prefetch folded after MFMA.
//  - exchange-latency line CLOSED (V9-V12).
// ---------------------------------------------------------------------------

typedef __attribute__((ext_vector_type(8))) short short8;
typedef __attribute__((ext_vector_type(4))) float f32x4;

static constexpr int Bn = 64, Sn = 512, Dn = 768, Wn = 256, Hn = 384, Cn = 425;
static constexpr int G4H = 4 * Hn;          // 1536
static constexpr int NBT = 4;               // batch tiles of 16
static constexpr int NCK = 6;               // h-chunks of 64 rows per dir
static constexpr int NRWG = 2 * NBT * NCK;  // 48 recur wgs

__device__ __forceinline__ unsigned short f2bf(float f) {
  unsigned int u = __float_as_uint(f);
  u += 0x7FFFu + ((u >> 16) & 1u);          // round-to-nearest-even
  return (unsigned short)(u >> 16);
}
__device__ __forceinline__ float bf2f(unsigned short h) {
  return __uint_as_float(((unsigned int)h) << 16);
}
__device__ __forceinline__ float sigm(float x)  { return 1.f / (1.f + __expf(-x)); }
__device__ __forceinline__ float tanhft(float x){ return 1.f - 2.f / (__expf(2.f * x) + 1.f); }

// async global->LDS, 16B per lane; LDS dest = wave-uniform base + lane*16
#define GLL16(gp, lp) __builtin_amdgcn_global_load_lds( \
  (const __attribute__((address_space(1))) unsigned int*)(gp), \
  (__attribute__((address_space(3))) unsigned int*)(lp), 16, 0, 0)

// ---------------------------------------------------------------------------
// zero comm region through the UC/atomic path (visible to agent-scope loads)
__global__ void zero_comm(unsigned int* p, int nwords) {
  int i = blockIdx.x * 256 + threadIdx.x;
  if (i < nwords)
    __hip_atomic_store(&p[i], 0u, __ATOMIC_RELAXED, __HIP_MEMORY_SCOPE_AGENT);
}

// ---------------------------------------------------------------------------
__global__ void scan_starts(const int* __restrict__ counts, int* __restrict__ starts) {
  int b = blockIdx.x, j = threadIdx.x;      // 64 blocks x 256 threads
  __shared__ int sm[256];
  int c = counts[b * Wn + j];
  sm[j] = c;
  __syncthreads();
  for (int off = 1; off < 256; off <<= 1) {
    int v = (j >= off) ? sm[j - off] : 0;
    __syncthreads();
    sm[j] += v;
    __syncthreads();
  }
  starts[b * Wn + j] = sm[j] - c;           // exclusive
}

// ---------------------------------------------------------------------------
__global__ void prep_cast(const float* __restrict__ Wih_f, const float* __restrict__ Wih_b,
                          const float* __restrict__ Whh_f, const float* __restrict__ Whh_b,
                          const float* __restrict__ Wlin,
                          const float* __restrict__ bih_f, const float* __restrict__ bhh_f,
                          const float* __restrict__ bih_b, const float* __restrict__ bhh_b,
                          unsigned short* __restrict__ wih, unsigned short* __restrict__ whh,
                          unsigned short* __restrict__ wlin, float* __restrict__ biasc) {
  int i = blockIdx.x * 256 + threadIdx.x;
  const int T0 = 3072 * 768;                // Wih both dirs
  const int T1 = 2 * 1536 * 384;            // Whh both dirs
  const int T2 = Cn * 768;                  // Wlin
  const int T3 = 3072;                      // bias
  if (i < T0) {
    int n = i / 768, k = i - n * 768;
    float v = (n < 1536) ? Wih_f[n * 768 + k] : Wih_b[(n - 1536) * 768 + k];
    wih[i] = f2bf(v);
  } else if (i < T0 + T1) {
    int j = i - T0;
    float v = (j < 1536 * 384) ? Whh_f[j] : Whh_b[j - 1536 * 384];
    whh[j] = f2bf(v);
  } else if (i < T0 + T1 + T2) {
    int j = i - T0 - T1;
    wlin[j] = f2bf(Wlin[j]);
  } else if (i < T0 + T1 + T2 + T3) {
    int n = i - T0 - T1 - T2;
    biasc[n] = (n < 1536) ? (bih_f[n] + bhh_f[n]) : (bih_b[n - 1536] + bhh_b[n - 1536]);
  }
}

// ---------------------------------------------------------------------------
// ragged segment mean -> f0p rows [s*64+b][768]
__global__ void pool_kernel(const float* __restrict__ f0, const int* __restrict__ counts,
                            const int* __restrict__ starts, unsigned short* __restrict__ f0p) {
  int idx = blockIdx.x * 256 + threadIdx.x;           // B*S*192 exact
  int dc = idx % 192;
  int rest = idx / 192;
  int s = rest & 511, b = rest >> 9;
  const float4* f4 = (const float4*)f0;
  float4 v;
  if (s < Wn) {
    int st = starts[b * Wn + s], cnt = counts[b * Wn + s];
    v = f4[(size_t)(b * Sn + st) * 192 + dc];
    if (cnt == 2) {
      float4 v2 = f4[(size_t)(b * Sn + st + 1) * 192 + dc];
      v.x = (v.x + v2.x) * 0.5f; v.y = (v.y + v2.y) * 0.5f;
      v.z = (v.z + v2.z) * 0.5f; v.w = (v.w + v2.w) * 0.5f;
    }
  } else {
    v = f4[(size_t)(b * Sn + s) * 192 + dc];
  }
  ushort4 o;
  o.x = f2bf(v.x); o.y = f2bf(v.y); o.z = f2bf(v.z); o.w = f2bf(v.w);
  ((ushort4*)f0p)[(size_t)(s * Bn + b) * 192 + dc] = o;
}

// ---------------------------------------------------------------------------
// FUSED: recur (bid<48) + xp GEMM (bid>=48). 84KB LDS -> 1 wg/CU.
// f0h: f0p rows [s*64+b][768]; recur overwrites row (t*64+b) with h_all.
// xp : [2][512][64][1536] bf16, written via full-sector u64 AGENT atomics.
// gcnt[32]: group counters (8 mtiles x 24 ntiles = 192 per group).
// htag: [2][2][64][384] u32 = (tag<<16)|bf16 agent mailbox (V8-exact).
__global__ void __launch_bounds__(256, 1)
fused_kernel(const unsigned short* __restrict__ whh,   // [2][1536][384] bf16
             unsigned short* xp,                        // in/out (both roles)
             unsigned short* f0h,                       // f0p in, h_all out (overlay)
             const unsigned short* __restrict__ wih,    // [3072][768] bf16
             const float* __restrict__ biasc,           // [3072]
             unsigned int* htag,
             unsigned int* gcnt) {
  // 84KB static LDS: 1 wg/CU (CUs private). Epilogue stage fits (33KB).
  __shared__ __align__(16) char smem[86016];
  int bid = blockIdx.x;
  int tid = threadIdx.x, w = tid >> 6, l = tid & 63, lr = l & 15, lq = l >> 4;

  if (bid < NRWG) {
    // ================= recurrence (V8-exact core) =================
    int dir = bid / (NBT * NCK);
    int rem = bid % (NBT * NCK);
    int btile = rem / NCK, chunk = rem % NCK;
    int hwb = chunk * 64 + w * 16;
    int pr = tid >> 4, pk = tid & 15;
    unsigned int (*hlds)[16 * 196] = (unsigned int (*)[16 * 196])smem;

    short8 bfr[4][12];
#pragma unroll
    for (int q = 0; q < 4; ++q)
#pragma unroll
      for (int kf = 0; kf < 12; ++kf)
        bfr[q][kf] = *(const short8*)&whh[((size_t)dir * 1536 + q * 384 + hwb + lr) * 384 + kf * 32 + lq * 8];

    // xp readiness gate: group g = t>>4 ready when gcnt[g]==192
    int lastG = -1;
    auto gate = [&](int tt) {
      int g = tt >> 4;
      if (g != lastG) {
        while (__hip_atomic_load(&gcnt[g], __ATOMIC_RELAXED, __HIP_MEMORY_SCOPE_AGENT) < 192u)
          __builtin_amdgcn_s_sleep(4);
        lastG = g;
        asm volatile("" ::: "memory");      // no xp load hoisting above the gate
      }
    };
    auto ldxp = [&](int tt, unsigned short* dst) {
#pragma unroll
      for (int q = 0; q < 4; ++q)
#pragma unroll
        for (int r = 0; r < 4; ++r) {
          int b = btile * 16 + lq * 4 + r;
          dst[q * 4 + r] = xp[((size_t)((dir * Sn + tt) * Bn + b)) * 1536 + q * 384 + hwb + lr];
        }
    };
    unsigned short xcur[16], xnxt[16];
    int t0 = dir ? (Sn - 1) : 0;
    gate(t0);
    ldxp(t0, xcur);

    f32x4 c0 = (f32x4){0.f, 0.f, 0.f, 0.f};

    for (int it = 0; it < Sn; ++it) {
      int t = dir ? (Sn - 1 - it) : it;
      int tn = (it + 1 < Sn) ? (dir ? (Sn - 2 - it) : (it + 1)) : t;
      gate(tn);
      ldxp(tn, xnxt);                       // issued now, consumed at loop end

      f32x4 acc[4];
#pragma unroll
      for (int q = 0; q < 4; ++q) acc[q] = (f32x4){0.f, 0.f, 0.f, 0.f};

      if (it > 0) {
        const unsigned int expT = (unsigned int)it;
        int slot = (it - 1) & 1;
        const unsigned long long* srow = (const unsigned long long*)
            (htag + (size_t)(dir * 2 + slot) * 64 * 384 + (size_t)(btile * 16 + pr) * 384);
        unsigned long long v[12];
        while (true) {                      // V8 speculative tagged spin
          bool ok = true;
#pragma unroll
          for (int i = 0; i < 12; ++i) {
            unsigned long long x = __hip_atomic_load(&srow[pk + 16 * i],
                                     __ATOMIC_RELAXED, __HIP_MEMORY_SCOPE_AGENT);
            v[i] = x;
            ok &= (((unsigned int)(x >> 16) & 0xffffu) == expT) &
                  ((unsigned int)(x >> 48) == expT);
          }
          if (__all((int)ok)) break;
          __builtin_amdgcn_s_sleep(1);
        }
        unsigned int* dst = hlds[it & 1];
#pragma unroll
        for (int i = 0; i < 12; ++i)
          dst[pr * 196 + pk + 16 * i] = ((unsigned int)v[i] & 0xffffu) |
                                        (((unsigned int)(v[i] >> 32) & 0xffffu) << 16);
        __syncthreads();                    // the ONLY barrier per step
        const char* src = (const char*)hlds[it & 1];
#pragma unroll
        for (int kf = 0; kf < 12; ++kf) {
          short8 a = *(const short8*)(src + lr * 784 + kf * 64 + lq * 16);
#pragma unroll
          for (int q = 0; q < 4; ++q)
            acc[q] = __builtin_amdgcn_mfma_f32_16x16x32_bf16(a, bfr[q][kf], acc[q], 0, 0, 0);
        }
      }

      // cell (xp folded here) + publish (producer NEVER waits)
      unsigned int outTag = (unsigned int)(it + 1) << 16;
      int oslot = it & 1;
      unsigned int* obase = htag + (size_t)(dir * 2 + oslot) * 64 * 384;
      unsigned short hb16v[4];
#pragma unroll
      for (int r = 0; r < 4; ++r) {
        float iv = sigm(acc[0][r] + bf2f(xcur[0 * 4 + r]));
        float fv = sigm(acc[1][r] + bf2f(xcur[1 * 4 + r]));
        float gv = tanhft(acc[2][r] + bf2f(xcur[2 * 4 + r]));
        float ov = sigm(acc[3][r] + bf2f(xcur[3 * 4 + r]));
        float cf = fv * c0[r] + iv * gv;
        c0[r] = cf;
        float hv = ov * tanhft(cf);
        hb16v[r] = f2bf(hv);
        int b = btile * 16 + lq * 4 + r;
        __hip_atomic_store(&obase[(size_t)b * 384 + hwb + lr],
                           outTag | hb16v[r], __ATOMIC_RELAXED, __HIP_MEMORY_SCOPE_AGENT);
      }
#pragma unroll
      for (int r = 0; r < 4; ++r) {         // h_all row (t*64+b): clobbers only f0p(t)
        int b = btile * 16 + lq * 4 + r;
        f0h[((size_t)(t * Bn + b)) * 768 + dir * Hn + hwb + lr] = hb16v[r];
      }
#pragma unroll
      for (int i = 0; i < 16; ++i) xcur[i] = xnxt[i];
    }
    return;
  }

  // ================= xp GEMM tile =================
  // priority map: early blocks produce mtiles from both t-ends.
  int gb = bid - NRWG;                      // 0..6143
  int q = gb / 48, r = gb % 48;
  int mtile = (r < 24) ? q : (255 - q);     // 256 mtiles (2 t x 64 b each)
  int ntile = r % 24;                       // 24 ntiles
  unsigned short* As = (unsigned short*)smem;
  unsigned short* Bs = (unsigned short*)(smem + 8192);
  int mBase = mtile * 128, nBase = ntile * 128;
  int mw = (w & 1) * 64, nw = (w >> 1) * 64;
  f32x4 acc[4][4];
#pragma unroll
  for (int mt = 0; mt < 4; ++mt)
#pragma unroll
    for (int nt = 0; nt < 4; ++nt) acc[mt][nt] = (f32x4){0.f, 0.f, 0.f, 0.f};

  for (int kb = 0; kb < 24; ++kb) {
    int k0 = kb * 32;
#pragma unroll
    for (int j = 0; j < 2; ++j) {
      int g = j * 256 + tid;
      int row = g >> 2, kc = (g & 3) * 8;
      GLL16(f0h + (size_t)(mBase + row) * 768 + k0 + kc, (char*)As + (j * 256 + w * 64) * 16);
      GLL16(wih + (size_t)(nBase + row) * 768 + k0 + kc, (char*)Bs + (j * 256 + w * 64) * 16);
    }
    __syncthreads();
    short8 af[4], bfv[4];
#pragma unroll
    for (int mt = 0; mt < 4; ++mt) af[mt] = *(const short8*)&As[(mw + mt * 16 + lr) * 32 + lq * 8];
#pragma unroll
    for (int nt = 0; nt < 4; ++nt) bfv[nt] = *(const short8*)&Bs[(nw + nt * 16 + lr) * 32 + lq * 8];
#pragma unroll
    for (int mt = 0; mt < 4; ++mt)
#pragma unroll
      for (int nt = 0; nt < 4; ++nt)
        acc[mt][nt] = __builtin_amdgcn_mfma_f32_16x16x32_bf16(af[mt], bfv[nt], acc[mt][nt], 0, 0, 0);
    __syncthreads();
  }
  // ---- V15 epilogue: LDS stage (+bias) -> full-sector u64 agent stores ----
  // stage: [128 rows][132 u16] (stride 132 de-conflicts the u64 re-read)
  unsigned short* stage = (unsigned short*)smem;  // 33.8KB, As/Bs dead
#pragma unroll
  for (int nt = 0; nt < 4; ++nt) {
    int n = nBase + nw + nt * 16 + lr;
    float bias = biasc[n];
#pragma unroll
    for (int mt = 0; mt < 4; ++mt)
#pragma unroll
      for (int rr = 0; rr < 4; ++rr)
        stage[(mw + mt * 16 + lq * 4 + rr) * 132 + nw + nt * 16 + lr] =
            f2bf(acc[mt][nt][rr] + bias);
  }
  __syncthreads();
  {
    // tile n-range is d-uniform (nBase multiple of 128, 1536 boundary aligned)
    int d = (nBase >= 1536) ? 1 : 0;
    int gI0 = nBase - d * 1536;
    int g8 = l >> 3, sub = l & 7;           // 8-lane groups fill 64B sectors
#pragma unroll
    for (int i = 0; i < 16; ++i) {
      int row = w * 32 + (i & 3) * 8 + g8;  // 4 row-octets
      int s = i >> 2;                       // 4 sectors per row (256B)
      int m = mBase + row, t2 = m >> 6, b2 = m & 63;
      unsigned long long val;
      memcpy(&val, &stage[row * 132 + s * 32 + sub * 4], 8);
      unsigned long long* dp = (unsigned long long*)
          (xp + ((size_t)((d * Sn + t2) * Bn + b2)) * 1536 + gI0) + s * 8 + sub;
      __hip_atomic_store(dp, val, __ATOMIC_RELAXED, __HIP_MEMORY_SCOPE_AGENT);
    }
  }
  asm volatile("s_waitcnt vmcnt(0)" ::: "memory");      // all stores at IC
  __syncthreads();                                       // whole wg drained
  if (tid == 0)
    __hip_atomic_fetch_add(&gcnt[mtile >> 3], 1u, __ATOMIC_RELAXED,
                           __HIP_MEMORY_SCOPE_AGENT);
}

// ---------------------------------------------------------------------------
// out GEMM: A = h_all rows [t*64+b][768] bf16, B = wlin [425][768] bf16
// out[(b*S+t)*C + n] fp32 = A@B^T + blin
__global__ void gemm_out(const unsigned short* __restrict__ A, const unsigned short* __restrict__ Bw,
                         const float* __restrict__ blin, float* __restrict__ out) {
  __shared__ __align__(16) unsigned short As[128 * 32];
  __shared__ __align__(16) unsigned short Bs[128 * 32];
  int tid = threadIdx.x, w = tid >> 6, l = tid & 63, lr = l & 15, lq = l >> 4;
  int mBase = blockIdx.x * 128, nBase = blockIdx.y * 128;
  int mw = (w & 1) * 64, nw = (w >> 1) * 64;
  f32x4 acc[4][4];
#pragma unroll
  for (int mt = 0; mt < 4; ++mt)
#pragma unroll
    for (int nt = 0; nt < 4; ++nt) acc[mt][nt] = (f32x4){0.f, 0.f, 0.f, 0.f};

  for (int kb = 0; kb < 24; ++kb) {
    int k0 = kb * 32;
#pragma unroll
    for (int j = 0; j < 2; ++j) {
      int g = j * 256 + tid;
      int row = g >> 2, kc = (g & 3) * 8;
      int nr = nBase + row; if (nr > Cn - 1) nr = Cn - 1;   // clamp: Wlin has 425 rows
      GLL16(A + (size_t)(mBase + row) * 768 + k0 + kc, (char*)As + (j * 256 + w * 64) * 16);
      GLL16(Bw + (size_t)nr * 768 + k0 + kc, (char*)Bs + (j * 256 + w * 64) * 16);
    }
    __syncthreads();
    short8 af[4], bfv[4];
#pragma unroll
    for (int mt = 0; mt < 4; ++mt) af[mt] = *(const short8*)&As[(mw + mt * 16 + lr) * 32 + lq * 8];
#pragma unroll
    for (int nt = 0; nt < 4; ++nt) bfv[nt] = *(const short8*)&Bs[(nw + nt * 16 + lr) * 32 + lq * 8];
#pragma unroll
    for (int mt = 0; mt < 4; ++mt)
#pragma unroll
      for (int nt = 0; nt < 4; ++nt)
        acc[mt][nt] = __builtin_amdgcn_mfma_f32_16x16x32_bf16(af[mt], bfv[nt], acc[mt][nt], 0, 0, 0);
    __syncthreads();
  }
#pragma unroll
  for (int nt = 0; nt < 4; ++nt) {
    int n = nBase + nw + nt * 16 + lr;
    if (n < Cn) {
      float bias = blin[n];
#pragma unroll
      for (int mt = 0; mt < 4; ++mt) {
#pragma unroll
        for (int r = 0; r < 4; ++r) {
          int m = mBase + mw + mt * 16 + lq * 4 + r;
          int t = m >> 6, b = m & 63;       // rows are [t*64+b]
          out[((size_t)(b * Sn + t)) * Cn + n] = acc[mt][nt][r] + bias;
        }
      }
    }
  }
}

// ---------------------------------------------------------------------------
extern "C" void kernel_launch(void* const* d_in, const int* in_sizes, int n_in,
                              void* d_out, int out_size, void* d_ws, size_t ws_size,
                              hipStream_t stream) {
  (void)in_sizes; (void)n_in; (void)out_size;
  const float* f0     = (const float*)d_in[0];
  const int*   counts = (const int*)  d_in[1];
  const float* Wih_f  = (const float*)d_in[2];
  const float* Whh_f  = (const float*)d_in[3];
  const float* bih_f  = (const float*)d_in[4];
  const float* bhh_f  = (const float*)d_in[5];
  const float* Wih_b  = (const float*)d_in[6];
  const float* Whh_b  = (const float*)d_in[7];
  const float* bih_b  = (const float*)d_in[8];
  const float* bhh_b  = (const float*)d_in[9];
  const float* Wlin   = (const float*)d_in[10];
  const float* blin   = (const float*)d_in[11];
  float* out = (float*)d_out;

  char* ws = (char*)d_ws;
  size_t o = 0;
  auto alloc = [&](size_t bytes) { size_t cur = o; o += (bytes + 255) & ~(size_t)255; return cur; };
  size_t o_f0p    = alloc((size_t)Bn * Sn * Dn * 2);        // 50.3 MB (f0p; overlaid h_all)
  size_t o_xp     = alloc((size_t)2 * Sn * Bn * G4H * 2);   // 201.3 MB
  size_t o_wih    = alloc((size_t)3072 * 768 * 2);
  size_t o_whh    = alloc((size_t)2 * 1536 * 384 * 2);
  size_t o_wlin   = alloc((size_t)Cn * 768 * 2);
  size_t o_bias   = alloc((size_t)3072 * 4);
  size_t o_starts = alloc((size_t)Bn * Wn * 4);
  size_t o_htag   = alloc((size_t)2 * 2 * 64 * 384 * 4);    // 384 KB, [dir][slot][b][h]
  size_t o_gcnt   = alloc((size_t)32 * 4);                  // contiguous after htag
  if (o > ws_size) return;  // ~261 MiB of workspace

  unsigned short* f0h   = (unsigned short*)(ws + o_f0p);
  unsigned short* xp    = (unsigned short*)(ws + o_xp);
  unsigned short* wih   = (unsigned short*)(ws + o_wih);
  unsigned short* whh   = (unsigned short*)(ws + o_whh);
  unsigned short* wlin  = (unsigned short*)(ws + o_wlin);
  float*          biasc = (float*)(ws + o_bias);
  int*            starts= (int*)(ws + o_starts);
  unsigned int*   htag  = (unsigned int*)(ws + o_htag);
  unsigned int*   gcnt  = (unsigned int*)(ws + o_gcnt);

  {
    int nwords = 2 * 2 * 64 * 384 + 32;                     // htag + gcnt (contiguous)
    zero_comm<<<(nwords + 255) / 256, 256, 0, stream>>>(htag, nwords);
  }
  scan_starts<<<Bn, 256, 0, stream>>>(counts, starts);
  {
    int total = 3072 * 768 + 2 * 1536 * 384 + Cn * 768 + 3072;
    prep_cast<<<(total + 255) / 256, 256, 0, stream>>>(Wih_f, Wih_b, Whh_f, Whh_b, Wlin,
                                                       bih_f, bhh_f, bih_b, bhh_b,
                                                       wih, whh, wlin, biasc);
  }
  pool_kernel<<<(Bn * Sn * 192) / 256, 256, 0, stream>>>(f0, counts, starts, f0h);
  fused_kernel<<<NRWG + 6144, 256, 0, stream>>>(whh, xp, f0h, wih, biasc, htag, gcnt);
  gemm_out<<<dim3(256, 4), 256, 0, stream>>>(f0h, wlin, blin, out);
}

// Round 10
// 1623.158 us; speedup vs baseline: 4.2783x; 1.0042x over previous
//
#include <hip/hip_runtime.h>
#include <stdint.h>

// ---------------------------------------------------------------------------
// LSTMSupertaggingModel: segment-mean-pool -> BiLSTM(H=384) -> Linear(C=425)
// B=64, S=512, D=768, W=256, H=384, C=425
//
// V16 = V15 with the consumer spin restructured into SPLIT PHASES:
//   phase 1: issue all 12 agent atomic loads (NO uses between them);
//   phase 2: validate the 24 embedded tags.
// Rationale: V8..V15 all used load+check interleaved in one loop -> the
// compiler inserts a waitcnt before each check -> up to 12 SERIAL IC
// round-trips per spin round. That serialization is the only theory that
// explains 6600 cy/step vs the ~2100 cy floor (V12 tried to test it with
// inline asm and the container died; this is the zero-risk source-level
// form -- identical semantics, just reordered lane-local ops, giving
// LLVM's load clusterer the chance to batch the 12 loads into one RT).
//  - V15 lessons kept: IC atomic PIPELINE OP COUNT is the contended
//    resource (64 u16 -> 16 u64 epilogue stores bought -278us with FETCH
//    unchanged); full-sector u64 agent stores everywhere on bulk paths.
//  - V14 lesson kept: 84KB LDS (1 wg/CU) -- CU co-residency is irrelevant,
//    but private CUs are harmless; keep.
//  - V13 structure kept: fused recur+xp-GEMM (gemm rides free behind the
//    latency-bound recurrence), rows [s*64+b], gcnt gating, both-ends
//    priority, V8-exact mailbox, ldxp prefetch folded after MFMA.
//  - Bundled (separable, different kernels): zero_comm+scan_starts+
//    prep_cast merged into one block-range prep launch (saves ~2 launch
//    serializations; pool still ordered after scan by launch boundary).
// ---------------------------------------------------------------------------

typedef __attribute__((ext_vector_type(8))) short short8;
typedef __attribute__((ext_vector_type(4))) float f32x4;

static constexpr int Bn = 64, Sn = 512, Dn = 768, Wn = 256, Hn = 384, Cn = 425;
static constexpr int G4H = 4 * Hn;          // 1536
static constexpr int NBT = 4;               // batch tiles of 16
static constexpr int NCK = 6;               // h-chunks of 64 rows per dir
static constexpr int NRWG = 2 * NBT * NCK;  // 48 recur wgs

__device__ __forceinline__ unsigned short f2bf(float f) {
  unsigned int u = __float_as_uint(f);
  u += 0x7FFFu + ((u >> 16) & 1u);          // round-to-nearest-even
  return (unsigned short)(u >> 16);
}
__device__ __forceinline__ float bf2f(unsigned short h) {
  return __uint_as_float(((unsigned int)h) << 16);
}
__device__ __forceinline__ float sigm(float x)  { return 1.f / (1.f + __expf(-x)); }
__device__ __forceinline__ float tanhft(float x){ return 1.f - 2.f / (__expf(2.f * x) + 1.f); }

// async global->LDS, 16B per lane; LDS dest = wave-uniform base + lane*16
#define GLL16(gp, lp) __builtin_amdgcn_global_load_lds( \
  (const __attribute__((address_space(1))) unsigned int*)(gp), \
  (__attribute__((address_space(3))) unsigned int*)(lp), 16, 0, 0)

// ---------------------------------------------------------------------------
// merged prep: [0,ZB) zero htag+gcnt | [ZB,ZB+64) scan | [ZB+64,..) cast
static constexpr int COMMW = 2 * 2 * 64 * 384 + 32;   // htag + gcnt words
static constexpr int ZB = (COMMW + 255) / 256;        // 385 blocks
static constexpr int CASTN = 3072 * 768 + 2 * 1536 * 384 + Cn * 768 + 3072;
static constexpr int CB = (CASTN + 255) / 256;

__global__ void prep_kernel(unsigned int* __restrict__ comm,
                            const int* __restrict__ counts, int* __restrict__ starts,
                            const float* __restrict__ Wih_f, const float* __restrict__ Wih_b,
                            const float* __restrict__ Whh_f, const float* __restrict__ Whh_b,
                            const float* __restrict__ Wlin,
                            const float* __restrict__ bih_f, const float* __restrict__ bhh_f,
                            const float* __restrict__ bih_b, const float* __restrict__ bhh_b,
                            unsigned short* __restrict__ wih, unsigned short* __restrict__ whh,
                            unsigned short* __restrict__ wlin, float* __restrict__ biasc) {
  int bid = blockIdx.x;
  if (bid < ZB) {                           // zero comm (UC/atomic path)
    int i = bid * 256 + threadIdx.x;
    if (i < COMMW)
      __hip_atomic_store(&comm[i], 0u, __ATOMIC_RELAXED, __HIP_MEMORY_SCOPE_AGENT);
    return;
  }
  if (bid < ZB + 64) {                      // per-sentence exclusive scan
    int b = bid - ZB, j = threadIdx.x;
    __shared__ int sm[256];
    int c = counts[b * Wn + j];
    sm[j] = c;
    __syncthreads();
    for (int off = 1; off < 256; off <<= 1) {
      int v = (j >= off) ? sm[j - off] : 0;
      __syncthreads();
      sm[j] += v;
      __syncthreads();
    }
    starts[b * Wn + j] = sm[j] - c;
    return;
  }
  int i = (bid - ZB - 64) * 256 + threadIdx.x;
  const int T0 = 3072 * 768;
  const int T1 = 2 * 1536 * 384;
  const int T2 = Cn * 768;
  const int T3 = 3072;
  if (i < T0) {
    int n = i / 768, k = i - n * 768;
    float v = (n < 1536) ? Wih_f[n * 768 + k] : Wih_b[(n - 1536) * 768 + k];
    wih[i] = f2bf(v);
  } else if (i < T0 + T1) {
    int j = i - T0;
    float v = (j < 1536 * 384) ? Whh_f[j] : Whh_b[j - 1536 * 384];
    whh[j] = f2bf(v);
  } else if (i < T0 + T1 + T2) {
    int j = i - T0 - T1;
    wlin[j] = f2bf(Wlin[j]);
  } else if (i < T0 + T1 + T2 + T3) {
    int n = i - T0 - T1 - T2;
    biasc[n] = (n < 1536) ? (bih_f[n] + bhh_f[n]) : (bih_b[n - 1536] + bhh_b[n - 1536]);
  }
}

// ---------------------------------------------------------------------------
// ragged segment mean -> f0p rows [s*64+b][768]
__global__ void pool_kernel(const float* __restrict__ f0, const int* __restrict__ counts,
                            const int* __restrict__ starts, unsigned short* __restrict__ f0p) {
  int idx = blockIdx.x * 256 + threadIdx.x;           // B*S*192 exact
  int dc = idx % 192;
  int rest = idx / 192;
  int s = rest & 511, b = rest >> 9;
  const float4* f4 = (const float4*)f0;
  float4 v;
  if (s < Wn) {
    int st = starts[b * Wn + s], cnt = counts[b * Wn + s];
    v = f4[(size_t)(b * Sn + st) * 192 + dc];
    if (cnt == 2) {
      float4 v2 = f4[(size_t)(b * Sn + st + 1) * 192 + dc];
      v.x = (v.x + v2.x) * 0.5f; v.y = (v.y + v2.y) * 0.5f;
      v.z = (v.z + v2.z) * 0.5f; v.w = (v.w + v2.w) * 0.5f;
    }
  } else {
    v = f4[(size_t)(b * Sn + s) * 192 + dc];
  }
  ushort4 o;
  o.x = f2bf(v.x); o.y = f2bf(v.y); o.z = f2bf(v.z); o.w = f2bf(v.w);
  ((ushort4*)f0p)[(size_t)(s * Bn + b) * 192 + dc] = o;
}

// ---------------------------------------------------------------------------
// FUSED: recur (bid<48) + xp GEMM (bid>=48). 84KB LDS -> 1 wg/CU.
// f0h: f0p rows [s*64+b][768]; recur overwrites row (t*64+b) with h_all.
// xp : [2][512][64][1536] bf16, written via full-sector u64 AGENT atomics.
// gcnt[32]: group counters (8 mtiles x 24 ntiles = 192 per group).
// htag: [2][2][64][384] u32 = (tag<<16)|bf16 agent mailbox (V8-exact).
__global__ void __launch_bounds__(256, 1)
fused_kernel(const unsigned short* __restrict__ whh,   // [2][1536][384] bf16
             unsigned short* xp,                        // in/out (both roles)
             unsigned short* f0h,                       // f0p in, h_all out (overlay)
             const unsigned short* __restrict__ wih,    // [3072][768] bf16
             const float* __restrict__ biasc,           // [3072]
             unsigned int* htag,
             unsigned int* gcnt) {
  // 84KB static LDS: 1 wg/CU (CUs private). Epilogue stage fits (33KB).
  __shared__ __align__(16) char smem[86016];
  int bid = blockIdx.x;
  int tid = threadIdx.x, w = tid >> 6, l = tid & 63, lr = l & 15, lq = l >> 4;

  if (bid < NRWG) {
    // ================= recurrence (V8 core, V16 split-phase spin) =========
    int dir = bid / (NBT * NCK);
    int rem = bid % (NBT * NCK);
    int btile = rem / NCK, chunk = rem % NCK;
    int hwb = chunk * 64 + w * 16;
    int pr = tid >> 4, pk = tid & 15;
    unsigned int (*hlds)[16 * 196] = (unsigned int (*)[16 * 196])smem;

    short8 bfr[4][12];
#pragma unroll
    for (int q = 0; q < 4; ++q)
#pragma unroll
      for (int kf = 0; kf < 12; ++kf)
        bfr[q][kf] = *(const short8*)&whh[((size_t)dir * 1536 + q * 384 + hwb + lr) * 384 + kf * 32 + lq * 8];

    // xp readiness gate: group g = t>>4 ready when gcnt[g]==192
    int lastG = -1;
    auto gate = [&](int tt) {
      int g = tt >> 4;
      if (g != lastG) {
        while (__hip_atomic_load(&gcnt[g], __ATOMIC_RELAXED, __HIP_MEMORY_SCOPE_AGENT) < 192u)
          __builtin_amdgcn_s_sleep(4);
        lastG = g;
        asm volatile("" ::: "memory");      // no xp load hoisting above the gate
      }
    };
    auto ldxp = [&](int tt, unsigned short* dst) {
#pragma unroll
      for (int q = 0; q < 4; ++q)
#pragma unroll
        for (int r = 0; r < 4; ++r) {
          int b = btile * 16 + lq * 4 + r;
          dst[q * 4 + r] = xp[((size_t)((dir * Sn + tt) * Bn + b)) * 1536 + q * 384 + hwb + lr];
        }
    };
    unsigned short xcur[16], xnxt[16];
    int t0 = dir ? (Sn - 1) : 0;
    gate(t0);
    ldxp(t0, xcur);

    f32x4 c0 = (f32x4){0.f, 0.f, 0.f, 0.f};

    for (int it = 0; it < Sn; ++it) {
      int t = dir ? (Sn - 1 - it) : it;
      int tn = (it + 1 < Sn) ? (dir ? (Sn - 2 - it) : (it + 1)) : t;
      gate(tn);
      ldxp(tn, xnxt);                       // issued now, consumed at loop end

      f32x4 acc[4];
#pragma unroll
      for (int q = 0; q < 4; ++q) acc[q] = (f32x4){0.f, 0.f, 0.f, 0.f};

      if (it > 0) {
        const unsigned int expT = (unsigned int)it;
        int slot = (it - 1) & 1;
        const unsigned long long* srow = (const unsigned long long*)
            (htag + (size_t)(dir * 2 + slot) * 64 * 384 + (size_t)(btile * 16 + pr) * 384);
        unsigned long long v[12];
        while (true) {                      // V16: SPLIT-PHASE spin round
          // phase 1: issue all 12 loads, NO uses between them -> the load
          // clusterer can batch them into one IC round-trip
#pragma unroll
          for (int i = 0; i < 12; ++i)
            v[i] = __hip_atomic_load(&srow[pk + 16 * i],
                                     __ATOMIC_RELAXED, __HIP_MEMORY_SCOPE_AGENT);
          // phase 2: validate tags
          bool ok = true;
#pragma unroll
          for (int i = 0; i < 12; ++i)
            ok &= (((unsigned int)(v[i] >> 16) & 0xffffu) == expT) &
                  ((unsigned int)(v[i] >> 48) == expT);
          if (__all((int)ok)) break;
          __builtin_amdgcn_s_sleep(1);
        }
        unsigned int* dst = hlds[it & 1];
#pragma unroll
        for (int i = 0; i < 12; ++i)
          dst[pr * 196 + pk + 16 * i] = ((unsigned int)v[i] & 0xffffu) |
                                        (((unsigned int)(v[i] >> 32) & 0xffffu) << 16);
        __syncthreads();                    // the ONLY barrier per step
        const char* src = (const char*)hlds[it & 1];
#pragma unroll
        for (int kf = 0; kf < 12; ++kf) {
          short8 a = *(const short8*)(src + lr * 784 + kf * 64 + lq * 16);
#pragma unroll
          for (int q = 0; q < 4; ++q)
            acc[q] = __builtin_amdgcn_mfma_f32_16x16x32_bf16(a, bfr[q][kf], acc[q], 0, 0, 0);
        }
      }

      // cell (xp folded here) + publish (producer NEVER waits)
      unsigned int outTag = (unsigned int)(it + 1) << 16;
      int oslot = it & 1;
      unsigned int* obase = htag + (size_t)(dir * 2 + oslot) * 64 * 384;
      unsigned short hb16v[4];
#pragma unroll
      for (int r = 0; r < 4; ++r) {
        float iv = sigm(acc[0][r] + bf2f(xcur[0 * 4 + r]));
        float fv = sigm(acc[1][r] + bf2f(xcur[1 * 4 + r]));
        float gv = tanhft(acc[2][r] + bf2f(xcur[2 * 4 + r]));
        float ov = sigm(acc[3][r] + bf2f(xcur[3 * 4 + r]));
        float cf = fv * c0[r] + iv * gv;
        c0[r] = cf;
        float hv = ov * tanhft(cf);
        hb16v[r] = f2bf(hv);
        int b = btile * 16 + lq * 4 + r;
        __hip_atomic_store(&obase[(size_t)b * 384 + hwb + lr],
                           outTag | hb16v[r], __ATOMIC_RELAXED, __HIP_MEMORY_SCOPE_AGENT);
      }
#pragma unroll
      for (int r = 0; r < 4; ++r) {         // h_all row (t*64+b): clobbers only f0p(t)
        int b = btile * 16 + lq * 4 + r;
        f0h[((size_t)(t * Bn + b)) * 768 + dir * Hn + hwb + lr] = hb16v[r];
      }
#pragma unroll
      for (int i = 0; i < 16; ++i) xcur[i] = xnxt[i];
    }
    return;
  }

  // ================= xp GEMM tile =================
  // priority map: early blocks produce mtiles from both t-ends.
  int gb = bid - NRWG;                      // 0..6143
  int q = gb / 48, r = gb % 48;
  int mtile = (r < 24) ? q : (255 - q);     // 256 mtiles (2 t x 64 b each)
  int ntile = r % 24;                       // 24 ntiles
  unsigned short* As = (unsigned short*)smem;
  unsigned short* Bs = (unsigned short*)(smem + 8192);
  int mBase = mtile * 128, nBase = ntile * 128;
  int mw = (w & 1) * 64, nw = (w >> 1) * 64;
  f32x4 acc[4][4];
#pragma unroll
  for (int mt = 0; mt < 4; ++mt)
#pragma unroll
    for (int nt = 0; nt < 4; ++nt) acc[mt][nt] = (f32x4){0.f, 0.f, 0.f, 0.f};

  for (int kb = 0; kb < 24; ++kb) {
    int k0 = kb * 32;
#pragma unroll
    for (int j = 0; j < 2; ++j) {
      int g = j * 256 + tid;
      int row = g >> 2, kc = (g & 3) * 8;
      GLL16(f0h + (size_t)(mBase + row) * 768 + k0 + kc, (char*)As + (j * 256 + w * 64) * 16);
      GLL16(wih + (size_t)(nBase + row) * 768 + k0 + kc, (char*)Bs + (j * 256 + w * 64) * 16);
    }
    __syncthreads();
    short8 af[4], bfv[4];
#pragma unroll
    for (int mt = 0; mt < 4; ++mt) af[mt] = *(const short8*)&As[(mw + mt * 16 + lr) * 32 + lq * 8];
#pragma unroll
    for (int nt = 0; nt < 4; ++nt) bfv[nt] = *(const short8*)&Bs[(nw + nt * 16 + lr) * 32 + lq * 8];
#pragma unroll
    for (int mt = 0; mt < 4; ++mt)
#pragma unroll
      for (int nt = 0; nt < 4; ++nt)
        acc[mt][nt] = __builtin_amdgcn_mfma_f32_16x16x32_bf16(af[mt], bfv[nt], acc[mt][nt], 0, 0, 0);
    __syncthreads();
  }
  // ---- V15 epilogue: LDS stage (+bias) -> full-sector u64 agent stores ----
  unsigned short* stage = (unsigned short*)smem;  // 33.8KB, As/Bs dead
#pragma unroll
  for (int nt = 0; nt < 4; ++nt) {
    int n = nBase + nw + nt * 16 + lr;
    float bias = biasc[n];
#pragma unroll
    for (int mt = 0; mt < 4; ++mt)
#pragma unroll
      for (int rr = 0; rr < 4; ++rr)
        stage[(mw + mt * 16 + lq * 4 + rr) * 132 + nw + nt * 16 + lr] =
            f2bf(acc[mt][nt][rr] + bias);
  }
  __syncthreads();
  {
    int d = (nBase >= 1536) ? 1 : 0;
    int gI0 = nBase - d * 1536;
    int g8 = l >> 3, sub = l & 7;           // 8-lane groups fill 64B sectors
#pragma unroll
    for (int i = 0; i < 16; ++i) {
      int row = w * 32 + (i & 3) * 8 + g8;  // 4 row-octets
      int s = i >> 2;                       // 4 sectors per row (256B)
      int m = mBase + row, t2 = m >> 6, b2 = m & 63;
      unsigned long long val;
      memcpy(&val, &stage[row * 132 + s * 32 + sub * 4], 8);
      unsigned long long* dp = (unsigned long long*)
          (xp + ((size_t)((d * Sn + t2) * Bn + b2)) * 1536 + gI0) + s * 8 + sub;
      __hip_atomic_store(dp, val, __ATOMIC_RELAXED, __HIP_MEMORY_SCOPE_AGENT);
    }
  }
  asm volatile("s_waitcnt vmcnt(0)" ::: "memory");      // all stores at IC
  __syncthreads();                                       // whole wg drained
  if (tid == 0)
    __hip_atomic_fetch_add(&gcnt[mtile >> 3], 1u, __ATOMIC_RELAXED,
                           __HIP_MEMORY_SCOPE_AGENT);
}

// ---------------------------------------------------------------------------
// out GEMM: A = h_all rows [t*64+b][768] bf16, B = wlin [425][768] bf16
// out[(b*S+t)*C + n] fp32 = A@B^T + blin
__global__ void gemm_out(const unsigned short* __restrict__ A, const unsigned short* __restrict__ Bw,
                         const float* __restrict__ blin, float* __restrict__ out) {
  __shared__ __align__(16) unsigned short As[128 * 32];
  __shared__ __align__(16) unsigned short Bs[128 * 32];
  int tid = threadIdx.x, w = tid >> 6, l = tid & 63, lr = l & 15, lq = l >> 4;
  int mBase = blockIdx.x * 128, nBase = blockIdx.y * 128;
  int mw = (w & 1) * 64, nw = (w >> 1) * 64;
  f32x4 acc[4][4];
#pragma unroll
  for (int mt = 0; mt < 4; ++mt)
#pragma unroll
    for (int nt = 0; nt < 4; ++nt) acc[mt][nt] = (f32x4){0.f, 0.f, 0.f, 0.f};

  for (int kb = 0; kb < 24; ++kb) {
    int k0 = kb * 32;
#pragma unroll
    for (int j = 0; j < 2; ++j) {
      int g = j * 256 + tid;
      int row = g >> 2, kc = (g & 3) * 8;
      int nr = nBase + row; if (nr > Cn - 1) nr = Cn - 1;   // clamp: Wlin has 425 rows
      GLL16(A + (size_t)(mBase + row) * 768 + k0 + kc, (char*)As + (j * 256 + w * 64) * 16);
      GLL16(Bw + (size_t)nr * 768 + k0 + kc, (char*)Bs + (j * 256 + w * 64) * 16);
    }
    __syncthreads();
    short8 af[4], bfv[4];
#pragma unroll
    for (int mt = 0; mt < 4; ++mt) af[mt] = *(const short8*)&As[(mw + mt * 16 + lr) * 32 + lq * 8];
#pragma unroll
    for (int nt = 0; nt < 4; ++nt) bfv[nt] = *(const short8*)&Bs[(nw + nt * 16 + lr) * 32 + lq * 8];
#pragma unroll
    for (int mt = 0; mt < 4; ++mt)
#pragma unroll
      for (int nt = 0; nt < 4; ++nt)
        acc[mt][nt] = __builtin_amdgcn_mfma_f32_16x16x32_bf16(af[mt], bfv[nt], acc[mt][nt], 0, 0, 0);
    __syncthreads();
  }
#pragma unroll
  for (int nt = 0; nt < 4; ++nt) {
    int n = nBase + nw + nt * 16 + lr;
    if (n < Cn) {
      float bias = blin[n];
#pragma unroll
      for (int mt = 0; mt < 4; ++mt) {
#pragma unroll
        for (int r = 0; r < 4; ++r) {
          int m = mBase + mw + mt * 16 + lq * 4 + r;
          int t = m >> 6, b = m & 63;       // rows are [t*64+b]
          out[((size_t)(b * Sn + t)) * Cn + n] = acc[mt][nt][r] + bias;
        }
      }
    }
  }
}

// ---------------------------------------------------------------------------
extern "C" void kernel_launch(void* const* d_in, const int* in_sizes, int n_in,
                              void* d_out, int out_size, void* d_ws, size_t ws_size,
                              hipStream_t stream) {
  (void)in_sizes; (void)n_in; (void)out_size;
  const float* f0     = (const float*)d_in[0];
  const int*   counts = (const int*)  d_in[1];
  const float* Wih_f  = (const float*)d_in[2];
  const float* Whh_f  = (const float*)d_in[3];
  const float* bih_f  = (const float*)d_in[4];
  const float* bhh_f  = (const float*)d_in[5];
  const float* Wih_b  = (const float*)d_in[6];
  const float* Whh_b  = (const float*)d_in[7];
  const float* bih_b  = (const float*)d_in[8];
  const float* bhh_b  = (const float*)d_in[9];
  const float* Wlin   = (const float*)d_in[10];
  const float* blin   = (const float*)d_in[11];
  float* out = (float*)d_out;

  char* ws = (char*)d_ws;
  size_t o = 0;
  auto alloc = [&](size_t bytes) { size_t cur = o; o += (bytes + 255) & ~(size_t)255; return cur; };
  size_t o_f0p    = alloc((size_t)Bn * Sn * Dn * 2);        // 50.3 MB (f0p; overlaid h_all)
  size_t o_xp     = alloc((size_t)2 * Sn * Bn * G4H * 2);   // 201.3 MB
  size_t o_wih    = alloc((size_t)3072 * 768 * 2);
  size_t o_whh    = alloc((size_t)2 * 1536 * 384 * 2);
  size_t o_wlin   = alloc((size_t)Cn * 768 * 2);
  size_t o_bias   = alloc((size_t)3072 * 4);
  size_t o_starts = alloc((size_t)Bn * Wn * 4);
  size_t o_htag   = alloc((size_t)2 * 2 * 64 * 384 * 4);    // 384 KB, [dir][slot][b][h]
  size_t o_gcnt   = alloc((size_t)32 * 4);                  // contiguous after htag
  if (o > ws_size) return;  // ~261 MiB of workspace

  unsigned short* f0h   = (unsigned short*)(ws + o_f0p);
  unsigned short* xp    = (unsigned short*)(ws + o_xp);
  unsigned short* wih   = (unsigned short*)(ws + o_wih);
  unsigned short* whh   = (unsigned short*)(ws + o_whh);
  unsigned short* wlin  = (unsigned short*)(ws + o_wlin);
  float*          biasc = (float*)(ws + o_bias);
  int*            starts= (int*)(ws + o_starts);
  unsigned int*   htag  = (unsigned int*)(ws + o_htag);
  unsigned int*   gcnt  = (unsigned int*)(ws + o_gcnt);
  (void)gcnt;

  prep_kernel<<<ZB + 64 + CB, 256, 0, stream>>>(htag, counts, starts,
                                                Wih_f, Wih_b, Whh_f, Whh_b, Wlin,
                                                bih_f, bhh_f, bih_b, bhh_b,
                                                wih, whh, wlin, biasc);
  pool_kernel<<<(Bn * Sn * 192) / 256, 256, 0, stream>>>(f0, counts, starts, f0h);
  fused_kernel<<<NRWG + 6144, 256, 0, stream>>>(whh, xp, f0h, wih, biasc, htag, gcnt);
  gemm_out<<<dim3(256, 4), 256, 0, stream>>>(f0h, wlin, blin, out);
}